// Round 3
// baseline (1614.021 us; speedup 1.0000x reference)
//
#include <hip/hip_runtime.h>

#define NN 50000
#define NE 800000
#define NG 2000
#define BN_EPS 1e-5f
#define NB_SCAN 196  // ceil(NN/256)
#define EPB 128      // edges per block in k_aggr_e

__device__ __forceinline__ float lrelu(float v) { return v > 0.f ? v : 0.01f * v; }

// ---- zero pool+cstats+stats+cnt
__global__ __launch_bounds__(256) void k_prep(int* __restrict__ p, int n)
{
    int tid = blockIdx.x * 256 + threadIdx.x;
    for (int i = tid; i < n; i += gridDim.x * 256) p[i] = 0;
}

// ---- histogram of dst
__global__ __launch_bounds__(256) void k_hist(const int* __restrict__ dst, int* __restrict__ cnt)
{
    int tid = blockIdx.x * 256 + threadIdx.x;
    for (int e = tid; e < NE; e += gridDim.x * 256) atomicAdd(&cnt[dst[e]], 1);
}

__global__ __launch_bounds__(256) void k_scanA(const int* __restrict__ cnt,
    int* __restrict__ off, int* __restrict__ bsum)
{
    __shared__ int s[256];
    int t = threadIdx.x;
    int i = blockIdx.x * 256 + t;
    int v = (i < NN) ? cnt[i] : 0;
    s[t] = v; __syncthreads();
    #pragma unroll
    for (int d = 1; d < 256; d <<= 1) {
        int u = (t >= d) ? s[t - d] : 0;
        __syncthreads();
        s[t] += u;
        __syncthreads();
    }
    if (i < NN) off[i + 1] = s[t];
    if (t == 255) bsum[blockIdx.x] = s[255];
}

__global__ __launch_bounds__(256) void k_scanB(const int* __restrict__ bsum, int* __restrict__ boff)
{
    __shared__ int s[256];
    int t = threadIdx.x;
    int v = (t < NB_SCAN) ? bsum[t] : 0;
    s[t] = v; __syncthreads();
    #pragma unroll
    for (int d = 1; d < 256; d <<= 1) {
        int u = (t >= d) ? s[t - d] : 0;
        __syncthreads();
        s[t] += u;
        __syncthreads();
    }
    boff[t] = s[t] - v;
}

__global__ __launch_bounds__(256) void k_scanC(const int* __restrict__ cnt,
    int* __restrict__ off, const int* __restrict__ boff, int* __restrict__ cur)
{
    int i = blockIdx.x * 256 + threadIdx.x;
    if (i < NN) {
        int incl = off[i + 1] + boff[blockIdx.x];
        off[i + 1] = incl;
        cur[i] = incl - cnt[i];
    }
    if (i == 0) off[0] = 0;
}

// ---- scatter edge ids into dst-sorted order (perm + srcs + dsts)
__global__ __launch_bounds__(256) void k_scatter(const int* __restrict__ src,
    const int* __restrict__ dst, int* __restrict__ cur,
    int* __restrict__ perm, int* __restrict__ srcs, int* __restrict__ dsts)
{
    int tid = blockIdx.x * 256 + threadIdx.x;
    for (int e = tid; e < NE; e += gridDim.x * 256) {
        int d = dst[e];
        int p = atomicAdd(&cur[d], 1);
        perm[p] = e;
        srcs[p] = src[e];
        dsts[p] = d;
    }
}

// ---- gather edge_attr into dst-sorted order: ea_s[p] = ea[perm[p]]
__global__ __launch_bounds__(256) void k_gather(const float* __restrict__ ea,
    const int* __restrict__ perm, float* __restrict__ eas)
{
    int tid = blockIdx.x * 256 + threadIdx.x;
    for (int i = tid; i < NE * 16; i += gridDim.x * 256) {
        int p = i >> 4, j = i & 15;
        eas[i] = ea[(size_t)perm[p] * 16 + j];
    }
}

// ---- aggr = (1+eps[l]) * x
__global__ __launch_bounds__(256) void k_init(const float* __restrict__ x,
    const float* __restrict__ eps, int layer, float* __restrict__ aggr)
{
    int tid = blockIdx.x * 256 + threadIdx.x;
    float s = 1.f + eps[layer];
    const float4* xv = (const float4*)x;
    float4* av = (float4*)aggr;
    for (int i = tid; i < NN * 16; i += gridDim.x * 256) {
        float4 v = xv[i];
        v.x *= s; v.y *= s; v.z *= s; v.w *= s;
        av[i] = v;
    }
}

// ---- edge-parallel: block owns EPB sorted edges; LDS accumulate per node slot;
// one global atomicAdd per (node,block) at flush.
__global__ __launch_bounds__(256) void k_aggr_e(
    const float* __restrict__ x, const float* __restrict__ eas,
    const int* __restrict__ srcs, const int* __restrict__ dsts,
    const int* __restrict__ off, const float* __restrict__ We,
    const float* __restrict__ be, float* __restrict__ aggr)
{
    __shared__ float acc[EPB * 64];
    __shared__ float ws[1024];   // transposed: ws[c*16+k] = We[k*64+c]
    __shared__ float bs[64];
    int t = threadIdx.x;
    for (int i = t; i < 1024; i += 256) {
        int c = i >> 4, k = i & 15;
        ws[i] = We[k * 64 + c];
    }
    if (t < 64) bs[t] = be[t];
    for (int i = t; i < EPB * 64; i += 256) acc[i] = 0.f;
    __syncthreads();
    int lane = t & 63, w = t >> 6;
    int E0 = blockIdx.x * EPB;
    int E1 = E0 + EPB; if (E1 > NE) E1 = NE;
    float bias = bs[lane];
    const float4* wv = (const float4*)(ws + lane * 16);
    float4 w0 = wv[0], w1 = wv[1], w2 = wv[2], w3 = wv[3];
    #pragma unroll 2
    for (int p = E0 + w; p < E1; p += 4) {
        int s = srcs[p], d = dsts[p];
        const float4* ap = (const float4*)(eas + (size_t)p * 16);
        float4 a0 = ap[0], a1 = ap[1], a2 = ap[2], a3 = ap[3];
        float xs = x[(size_t)s * 64 + lane];
        int o = off[d];
        int first = o > E0 ? o : E0;
        float m = bias;
        m = fmaf(a0.x, w0.x, m); m = fmaf(a0.y, w0.y, m);
        m = fmaf(a0.z, w0.z, m); m = fmaf(a0.w, w0.w, m);
        m = fmaf(a1.x, w1.x, m); m = fmaf(a1.y, w1.y, m);
        m = fmaf(a1.z, w1.z, m); m = fmaf(a1.w, w1.w, m);
        m = fmaf(a2.x, w2.x, m); m = fmaf(a2.y, w2.y, m);
        m = fmaf(a2.z, w2.z, m); m = fmaf(a2.w, w2.w, m);
        m = fmaf(a3.x, w3.x, m); m = fmaf(a3.y, w3.y, m);
        m = fmaf(a3.z, w3.z, m); m = fmaf(a3.w, w3.w, m);
        m += xs;
        m = fmaxf(m, 0.f);
        atomicAdd(&acc[(first - E0) * 64 + lane], m);
    }
    __syncthreads();
    for (int p = E0 + w; p < E1; p += 4) {
        int d = dsts[p];
        int o = off[d];
        int first = o > E0 ? o : E0;
        if (p == first)
            atomicAdd(&aggr[(size_t)d * 64 + lane], acc[(first - E0) * 64 + lane]);
    }
}

// ---- [N,64]@[64,64]+b. PRE=1: apply BN(statsIn,g,b)+lrelu to input rows.
template<int PRE, int POST>
__global__ __launch_bounds__(128) void k_mm64(
    const float* __restrict__ in, const float* __restrict__ W,
    const float* __restrict__ bias, const float* __restrict__ statsIn,
    const float* __restrict__ gIn, const float* __restrict__ bIn,
    float* __restrict__ out, float* __restrict__ statsOut)
{
    __shared__ float tile[128 * 65];
    __shared__ float sc[64], sh[64];
    int t = threadIdx.x;
    int base = blockIdx.x * 128;
    if (PRE) {
        if (t < 64) {
            float m = statsIn[t] * (1.f / NN);
            float v = statsIn[64 + t] * (1.f / NN) - m * m;
            float s = gIn[t] * rsqrtf(v + BN_EPS);
            sc[t] = s; sh[t] = bIn[t] - m * s;
        }
        __syncthreads();
    }
    for (int i = t; i < 2048; i += 128) {
        int row = i >> 4, c4 = (i & 15) << 2;
        int node = base + row;
        float4 v = {0.f, 0.f, 0.f, 0.f};
        if (node < NN) v = *(const float4*)(in + (size_t)node * 64 + c4);
        if (PRE) {
            v.x = lrelu(fmaf(v.x, sc[c4 + 0], sh[c4 + 0]));
            v.y = lrelu(fmaf(v.y, sc[c4 + 1], sh[c4 + 1]));
            v.z = lrelu(fmaf(v.z, sc[c4 + 2], sh[c4 + 2]));
            v.w = lrelu(fmaf(v.w, sc[c4 + 3], sh[c4 + 3]));
        }
        float* p = &tile[row * 65 + c4];
        p[0] = v.x; p[1] = v.y; p[2] = v.z; p[3] = v.w;
    }
    __syncthreads();
    float acc[64];
    #pragma unroll
    for (int c = 0; c < 64; ++c) acc[c] = bias[c];
    {
        const float* r = &tile[t * 65];
        for (int k = 0; k < 64; ++k) {
            float hk = r[k];
            #pragma unroll
            for (int c = 0; c < 64; ++c) acc[c] = fmaf(hk, W[k * 64 + c], acc[c]);
        }
    }
    __syncthreads();
    int node = base + t;
    bool valid = node < NN;
    #pragma unroll
    for (int c = 0; c < 64; ++c) tile[t * 65 + c] = valid ? acc[c] : 0.f;
    __syncthreads();
    for (int i = t; i < 2048; i += 128) {
        int row = i >> 4, c4 = (i & 15) << 2;
        int n2 = base + row;
        if (n2 < NN) {
            const float* p = &tile[row * 65 + c4];
            float4 v = {p[0], p[1], p[2], p[3]};
            if (POST == 1) { v.x = lrelu(v.x); v.y = lrelu(v.y); v.z = lrelu(v.z); v.w = lrelu(v.w); }
            *(float4*)(out + (size_t)n2 * 64 + c4) = v;
        }
    }
    if (POST == 0) {
        int c = t & 63, g = t >> 6;
        float s = 0.f, q = 0.f;
        for (int rr = 0; rr < 64; ++rr) {
            float v = tile[(g * 64 + rr) * 65 + c];
            s += v; q += v * v;
        }
        atomicAdd(&statsOut[c], s);
        atomicAdd(&statsOut[64 + c], q);
    }
}

// ---- elementwise x = lrelu(bn(h)) using stats
__global__ __launch_bounds__(256) void k_bn(
    const float* __restrict__ in, const float* __restrict__ stats,
    const float* __restrict__ g, const float* __restrict__ b,
    float* __restrict__ out)
{
    int tid = blockIdx.x * 256 + threadIdx.x;
    for (int i = tid; i < NN * 16; i += gridDim.x * 256) {
        int c4 = (i & 15) << 2;
        float4 v = ((const float4*)in)[i];
        float o[4] = {v.x, v.y, v.z, v.w};
        #pragma unroll
        for (int j = 0; j < 4; ++j) {
            int c = c4 + j;
            float m = stats[c] * (1.f / NN);
            float vv = stats[64 + c] * (1.f / NN) - m * m;
            float s = g[c] * rsqrtf(vv + BN_EPS);
            o[j] = lrelu(fmaf(o[j] - m, s, b[c]));
        }
        float4 r = {o[0], o[1], o[2], o[3]};
        ((float4*)out)[i] = r;
    }
}

__global__ __launch_bounds__(256) void k_pool(
    const float* __restrict__ x, const int* __restrict__ batch,
    float* __restrict__ pool)
{
    int lane = threadIdx.x & 63;
    int wid = (blockIdx.x * 256 + threadIdx.x) >> 6;
    int nw = (gridDim.x * 256) >> 6;
    for (int n = wid; n < NN; n += nw) {
        int gi = batch[n];
        atomicAdd(&pool[(size_t)gi * 64 + lane], x[(size_t)n * 64 + lane]);
    }
}

// ---- [N,128]@[128,128]+b with stats. MODE0: input = concat(x, pool[batch]).
template<int MODE>
__global__ __launch_bounds__(128) void k_cmm(
    const float* __restrict__ inA, const float* __restrict__ pool,
    const int* __restrict__ batch, const float* __restrict__ statsIn,
    const float* __restrict__ gIn, const float* __restrict__ bIn,
    const float* __restrict__ W, const float* __restrict__ bias,
    float* __restrict__ out, float* __restrict__ statsOut)
{
    __shared__ float tile[64 * 129];
    __shared__ float sc[128], sh[128];
    int t = threadIdx.x;
    int base = blockIdx.x * 64;
    if (MODE == 1) {
        float m = statsIn[t] * (1.f / NN);
        float v = statsIn[128 + t] * (1.f / NN) - m * m;
        float s = gIn[t] * rsqrtf(v + BN_EPS);
        sc[t] = s; sh[t] = bIn[t] - m * s;
        __syncthreads();
    }
    for (int i = t; i < 64 * 32; i += 128) {
        int row = i >> 5, c4 = (i & 31) << 2;
        int node = base + row;
        float4 v = {0.f, 0.f, 0.f, 0.f};
        if (node < NN) {
            if (MODE == 0) {
                if (c4 < 64) v = *(const float4*)(inA + (size_t)node * 64 + c4);
                else         v = *(const float4*)(pool + (size_t)batch[node] * 64 + (c4 - 64));
            } else {
                v = *(const float4*)(inA + (size_t)node * 128 + c4);
                v.x = lrelu(fmaf(v.x, sc[c4 + 0], sh[c4 + 0]));
                v.y = lrelu(fmaf(v.y, sc[c4 + 1], sh[c4 + 1]));
                v.z = lrelu(fmaf(v.z, sc[c4 + 2], sh[c4 + 2]));
                v.w = lrelu(fmaf(v.w, sc[c4 + 3], sh[c4 + 3]));
            }
        }
        float* p = &tile[row * 129 + c4];
        p[0] = v.x; p[1] = v.y; p[2] = v.z; p[3] = v.w;
    }
    __syncthreads();
    int lane = t & 63, half = t >> 6;
    float acc[64];
    #pragma unroll
    for (int c = 0; c < 64; ++c) acc[c] = bias[half * 64 + c];
    {
        const float* r = &tile[lane * 129];
        for (int k = 0; k < 128; ++k) {
            float hk = r[k];
            #pragma unroll
            for (int c = 0; c < 64; ++c) acc[c] = fmaf(hk, W[k * 128 + half * 64 + c], acc[c]);
        }
    }
    __syncthreads();
    int node = base + lane;
    bool valid = node < NN;
    #pragma unroll
    for (int c = 0; c < 64; ++c) tile[lane * 129 + half * 64 + c] = valid ? acc[c] : 0.f;
    __syncthreads();
    for (int i = t; i < 64 * 32; i += 128) {
        int row = i >> 5, c4 = (i & 31) << 2;
        int n2 = base + row;
        if (n2 < NN) {
            const float* p = &tile[row * 129 + c4];
            float4 v = {p[0], p[1], p[2], p[3]};
            *(float4*)(out + (size_t)n2 * 128 + c4) = v;
        }
    }
    {
        float s = 0.f, q = 0.f;
        for (int rr = 0; rr < 64; ++rr) {
            float v = tile[rr * 129 + t];
            s += v; q += v * v;
        }
        atomicAdd(&statsOut[t], s);
        atomicAdd(&statsOut[128 + t], q);
    }
}

// ---- out[n] = lrelu(bn(h128[n])) . cW3 + cb3
__global__ __launch_bounds__(256) void k_out(
    const float* __restrict__ h, const float* __restrict__ stats,
    const float* __restrict__ g, const float* __restrict__ b,
    const float* __restrict__ W3, const float* __restrict__ b3,
    float* __restrict__ outv)
{
    int lane = threadIdx.x & 63;
    int wid = (blockIdx.x * 256 + threadIdx.x) >> 6;
    int nw = (gridDim.x * 256) >> 6;
    float m0 = stats[lane] * (1.f / NN);
    float v0 = stats[128 + lane] * (1.f / NN) - m0 * m0;
    float s0 = g[lane] * rsqrtf(v0 + BN_EPS);
    float h0 = b[lane] - m0 * s0;
    float m1 = stats[64 + lane] * (1.f / NN);
    float v1 = stats[128 + 64 + lane] * (1.f / NN) - m1 * m1;
    float s1 = g[64 + lane] * rsqrtf(v1 + BN_EPS);
    float h1 = b[64 + lane] - m1 * s1;
    float w0 = W3[lane], w1 = W3[64 + lane];
    float bb = b3[0];
    for (int n = wid; n < NN; n += nw) {
        float a = h[(size_t)n * 128 + lane];
        float c = h[(size_t)n * 128 + 64 + lane];
        a = lrelu(fmaf(a, s0, h0));
        c = lrelu(fmaf(c, s1, h1));
        float p = a * w0 + c * w1;
        p += __shfl_xor(p, 32);
        p += __shfl_xor(p, 16);
        p += __shfl_xor(p, 8);
        p += __shfl_xor(p, 4);
        p += __shfl_xor(p, 2);
        p += __shfl_xor(p, 1);
        if (lane == 0) outv[n] = p + bb;
    }
}

extern "C" void kernel_launch(void* const* d_in, const int* in_sizes, int n_in,
                              void* d_out, int out_size, void* d_ws, size_t ws_size,
                              hipStream_t stream)
{
    const float* x0   = (const float*)d_in[0];
    const float* ea   = (const float*)d_in[1];
    const float* leW  = (const float*)d_in[2];
    const float* leb  = (const float*)d_in[3];
    const float* W1   = (const float*)d_in[4];
    const float* b1   = (const float*)d_in[5];
    const float* g1   = (const float*)d_in[6];
    const float* bb1  = (const float*)d_in[7];
    const float* W2   = (const float*)d_in[8];
    const float* b2   = (const float*)d_in[9];
    const float* eps  = (const float*)d_in[10];
    const float* og   = (const float*)d_in[11];
    const float* ob   = (const float*)d_in[12];
    const float* cW1  = (const float*)d_in[13];
    const float* cb1  = (const float*)d_in[14];
    const float* cg1  = (const float*)d_in[15];
    const float* cbb1 = (const float*)d_in[16];
    const float* cW2  = (const float*)d_in[17];
    const float* cb2  = (const float*)d_in[18];
    const float* cg2  = (const float*)d_in[19];
    const float* cbb2 = (const float*)d_in[20];
    const float* cW3  = (const float*)d_in[21];
    const float* cb3  = (const float*)d_in[22];
    const int* ei     = (const int*)d_in[23];
    const int* batch  = (const int*)d_in[24];
    const int* src = ei;
    const int* dst = ei + NE;

    // ---- workspace layout (4-byte units). ea_s aliases h128 (disjoint lifetimes).
    float* xbuf   = (float*)d_ws;                      // NN*64
    float* hbuf   = xbuf + (size_t)NN * 64;            // NN*64
    float* eas    = hbuf + (size_t)NN * 64;            // NE*16 (live: layers)
    float* h128   = eas;                               // NN*128 (live: head) — alias
    float* pool   = eas + (size_t)NE * 16;             // NG*64
    float* cstats = pool + (size_t)NG * 64;            // 512
    float* stats  = cstats + 512;                      // 768 (3 x 256)
    int*   cnt    = (int*)(stats + 768);               // NN
    int*   off    = cnt + NN;                          // NN+1 (+pad)
    int*   cur    = off + NN + 4;                      // NN
    int*   bsum   = cur + NN;                          // 256
    int*   boff   = bsum + 256;                        // 256
    int*   srcs   = boff + 256;                        // NE
    int*   dsts   = srcs + NE;                         // NE
    int*   perm   = dsts + NE;                         // NE
    float* outp   = (float*)d_out;

    int zeroN = NG * 64 + 512 + 768 + NN;  // pool..cnt contiguous

    int mmGrid = (NN + 127) / 128;   // 391
    int cGrid  = (NN + 63) / 64;     // 782
    int eGrid  = (NE + EPB - 1) / EPB;  // 6250

    // ---- CSR build + edge-attr pre-sort (once; reused by all 3 layers)
    k_prep<<<512, 256, 0, stream>>>((int*)pool, zeroN);
    k_hist<<<1024, 256, 0, stream>>>(dst, cnt);
    k_scanA<<<NB_SCAN, 256, 0, stream>>>(cnt, off, bsum);
    k_scanB<<<1, 256, 0, stream>>>(bsum, boff);
    k_scanC<<<NB_SCAN, 256, 0, stream>>>(cnt, off, boff, cur);
    k_scatter<<<1024, 256, 0, stream>>>(src, dst, cur, perm, srcs, dsts);
    k_gather<<<2048, 256, 0, stream>>>(ea, perm, eas);

    for (int l = 0; l < 3; ++l) {
        const float* xc = (l == 0) ? x0 : xbuf;
        float* st = stats + l * 256;
        k_init<<<1024, 256, 0, stream>>>(xc, eps, l, hbuf);
        k_aggr_e<<<eGrid, 256, 0, stream>>>(xc, eas, srcs, dsts, off,
                leW + l * 1024, leb + l * 64, hbuf);
        k_mm64<0, 0><<<mmGrid, 128, 0, stream>>>(hbuf, W1 + l * 4096, b1 + l * 64,
                nullptr, nullptr, nullptr, hbuf, st);
        if (l < 2) {
            k_mm64<1, 0><<<mmGrid, 128, 0, stream>>>(hbuf, W2 + l * 4096, b2 + l * 64,
                    st, g1 + l * 64, bb1 + l * 64, hbuf, st + 128);
            k_bn<<<1024, 256, 0, stream>>>(hbuf, st + 128, og + l * 64, ob + l * 64, xbuf);
        } else {
            k_mm64<1, 1><<<mmGrid, 128, 0, stream>>>(hbuf, W2 + l * 4096, b2 + l * 64,
                    st, g1 + l * 64, bb1 + l * 64, xbuf, nullptr);
        }
    }
    k_pool<<<1024, 256, 0, stream>>>(xbuf, batch, pool);
    k_cmm<0><<<cGrid, 128, 0, stream>>>(xbuf, pool, batch, nullptr, nullptr, nullptr,
                                        cW1, cb1, h128, cstats);
    k_cmm<1><<<cGrid, 128, 0, stream>>>(h128, nullptr, nullptr, cstats, cg1, cbb1,
                                        cW2, cb2, h128, cstats + 256);
    k_out<<<1024, 256, 0, stream>>>(h128, cstats + 256, cg2, cbb2, cW3, cb3, outp);
}

// Round 4
// 1077.112 us; speedup vs baseline: 1.4985x; 1.4985x over previous
//
#include <hip/hip_runtime.h>

#define NN 50000
#define NE 800000
#define NG 2000
#define BN_EPS 1e-5f
#define NB_SCAN 196  // ceil(NN/256)
#define CH 32        // edges per wave-chunk in k_aggr_s

__device__ __forceinline__ float lrelu(float v) { return v > 0.f ? v : 0.01f * v; }

// ---- zero pool+cstats+stats+cnt
__global__ __launch_bounds__(256) void k_prep(int* __restrict__ p, int n)
{
    int tid = blockIdx.x * 256 + threadIdx.x;
    for (int i = tid; i < n; i += gridDim.x * 256) p[i] = 0;
}

// ---- histogram of dst
__global__ __launch_bounds__(256) void k_hist(const int* __restrict__ dst, int* __restrict__ cnt)
{
    int tid = blockIdx.x * 256 + threadIdx.x;
    for (int e = tid; e < NE; e += gridDim.x * 256) atomicAdd(&cnt[dst[e]], 1);
}

__global__ __launch_bounds__(256) void k_scanA(const int* __restrict__ cnt,
    int* __restrict__ off, int* __restrict__ bsum)
{
    __shared__ int s[256];
    int t = threadIdx.x;
    int i = blockIdx.x * 256 + t;
    int v = (i < NN) ? cnt[i] : 0;
    s[t] = v; __syncthreads();
    #pragma unroll
    for (int d = 1; d < 256; d <<= 1) {
        int u = (t >= d) ? s[t - d] : 0;
        __syncthreads();
        s[t] += u;
        __syncthreads();
    }
    if (i < NN) off[i + 1] = s[t];
    if (t == 255) bsum[blockIdx.x] = s[255];
}

__global__ __launch_bounds__(256) void k_scanB(const int* __restrict__ bsum, int* __restrict__ boff)
{
    __shared__ int s[256];
    int t = threadIdx.x;
    int v = (t < NB_SCAN) ? bsum[t] : 0;
    s[t] = v; __syncthreads();
    #pragma unroll
    for (int d = 1; d < 256; d <<= 1) {
        int u = (t >= d) ? s[t - d] : 0;
        __syncthreads();
        s[t] += u;
        __syncthreads();
    }
    boff[t] = s[t] - v;
}

__global__ __launch_bounds__(256) void k_scanC(const int* __restrict__ cnt,
    int* __restrict__ off, const int* __restrict__ boff, int* __restrict__ cur)
{
    int i = blockIdx.x * 256 + threadIdx.x;
    if (i < NN) {
        int incl = off[i + 1] + boff[blockIdx.x];
        off[i + 1] = incl;
        cur[i] = incl - cnt[i];
    }
    if (i == 0) off[0] = 0;
}

// ---- scatter edge ids into dst-sorted order (perm + srcs + dsts)
__global__ __launch_bounds__(256) void k_scatter(const int* __restrict__ src,
    const int* __restrict__ dst, int* __restrict__ cur,
    int* __restrict__ perm, int* __restrict__ srcs, int* __restrict__ dsts)
{
    int tid = blockIdx.x * 256 + threadIdx.x;
    for (int e = tid; e < NE; e += gridDim.x * 256) {
        int d = dst[e];
        int p = atomicAdd(&cur[d], 1);
        perm[p] = e;
        srcs[p] = src[e];
        dsts[p] = d;
    }
}

// ---- gather edge_attr into dst-sorted order: ea_s[p] = ea[perm[p]]
__global__ __launch_bounds__(256) void k_gather(const float* __restrict__ ea,
    const int* __restrict__ perm, float* __restrict__ eas)
{
    int tid = blockIdx.x * 256 + threadIdx.x;
    for (int i = tid; i < NE * 16; i += gridDim.x * 256) {
        int p = i >> 4, j = i & 15;
        eas[i] = ea[(size_t)perm[p] * 16 + j];
    }
}

// ---- aggr = (1+eps[l]) * x
__global__ __launch_bounds__(256) void k_init(const float* __restrict__ x,
    const float* __restrict__ eps, int layer, float* __restrict__ aggr)
{
    int tid = blockIdx.x * 256 + threadIdx.x;
    float s = 1.f + eps[layer];
    const float4* xv = (const float4*)x;
    float4* av = (float4*)aggr;
    for (int i = tid; i < NN * 16; i += gridDim.x * 256) {
        float4 v = xv[i];
        v.x *= s; v.y *= s; v.z *= s; v.w *= s;
        av[i] = v;
    }
}

// ---- sorted-COO segment scan: wave owns CH contiguous sorted edges, lane=channel.
// All-register accumulation; global atomicAdd only on dst-change (~2-3 per chunk).
__global__ __launch_bounds__(256) void k_aggr_s(
    const float* __restrict__ x, const float* __restrict__ eas,
    const int* __restrict__ srcs, const int* __restrict__ dsts,
    const float* __restrict__ We, const float* __restrict__ be,
    float* __restrict__ aggr)
{
    __shared__ float ws[1024];   // transposed: ws[c*16+k] = We[k*64+c]
    __shared__ float bs[64];
    int t = threadIdx.x;
    for (int i = t; i < 1024; i += 256) {
        int c = i >> 4, k = i & 15;
        ws[i] = We[k * 64 + c];
    }
    if (t < 64) bs[t] = be[t];
    __syncthreads();
    int lane = t & 63;
    int chunk = blockIdx.x * 4 + (t >> 6);
    int c0 = chunk * CH;
    if (c0 >= NE) return;
    int c1 = c0 + CH; if (c1 > NE) c1 = NE;
    float bias = bs[lane];
    const float4* wv = (const float4*)(ws + lane * 16);
    float4 w0 = wv[0], w1 = wv[1], w2 = wv[2], w3 = wv[3];
    float acc = 0.f;
    int d = dsts[c0];
    #pragma unroll 4
    for (int p = c0; p < c1; ++p) {
        int s = srcs[p];
        const float4* ap = (const float4*)(eas + (size_t)p * 16);
        float4 a0 = ap[0], a1 = ap[1], a2 = ap[2], a3 = ap[3];
        float xs = x[(size_t)s * 64 + lane];
        float m = bias;
        m = fmaf(a0.x, w0.x, m); m = fmaf(a0.y, w0.y, m);
        m = fmaf(a0.z, w0.z, m); m = fmaf(a0.w, w0.w, m);
        m = fmaf(a1.x, w1.x, m); m = fmaf(a1.y, w1.y, m);
        m = fmaf(a1.z, w1.z, m); m = fmaf(a1.w, w1.w, m);
        m = fmaf(a2.x, w2.x, m); m = fmaf(a2.y, w2.y, m);
        m = fmaf(a2.z, w2.z, m); m = fmaf(a2.w, w2.w, m);
        m = fmaf(a3.x, w3.x, m); m = fmaf(a3.y, w3.y, m);
        m = fmaf(a3.z, w3.z, m); m = fmaf(a3.w, w3.w, m);
        m += xs;
        acc += fmaxf(m, 0.f);
        int dn = (p + 1 < c1) ? dsts[p + 1] : -1;
        if (dn != d) {
            atomicAdd(&aggr[(size_t)d * 64 + lane], acc);
            acc = 0.f;
            d = dn;
        }
    }
}

// ---- [N,64]@[64,64]+b. PRE=1: apply BN(statsIn,g,b)+lrelu to input rows.
template<int PRE, int POST>
__global__ __launch_bounds__(128) void k_mm64(
    const float* __restrict__ in, const float* __restrict__ W,
    const float* __restrict__ bias, const float* __restrict__ statsIn,
    const float* __restrict__ gIn, const float* __restrict__ bIn,
    float* __restrict__ out, float* __restrict__ statsOut)
{
    __shared__ float tile[128 * 65];
    __shared__ float sc[64], sh[64];
    int t = threadIdx.x;
    int base = blockIdx.x * 128;
    if (PRE) {
        if (t < 64) {
            float m = statsIn[t] * (1.f / NN);
            float v = statsIn[64 + t] * (1.f / NN) - m * m;
            float s = gIn[t] * rsqrtf(v + BN_EPS);
            sc[t] = s; sh[t] = bIn[t] - m * s;
        }
        __syncthreads();
    }
    for (int i = t; i < 2048; i += 128) {
        int row = i >> 4, c4 = (i & 15) << 2;
        int node = base + row;
        float4 v = {0.f, 0.f, 0.f, 0.f};
        if (node < NN) v = *(const float4*)(in + (size_t)node * 64 + c4);
        if (PRE) {
            v.x = lrelu(fmaf(v.x, sc[c4 + 0], sh[c4 + 0]));
            v.y = lrelu(fmaf(v.y, sc[c4 + 1], sh[c4 + 1]));
            v.z = lrelu(fmaf(v.z, sc[c4 + 2], sh[c4 + 2]));
            v.w = lrelu(fmaf(v.w, sc[c4 + 3], sh[c4 + 3]));
        }
        float* p = &tile[row * 65 + c4];
        p[0] = v.x; p[1] = v.y; p[2] = v.z; p[3] = v.w;
    }
    __syncthreads();
    float acc[64];
    #pragma unroll
    for (int c = 0; c < 64; ++c) acc[c] = bias[c];
    {
        const float* r = &tile[t * 65];
        for (int k = 0; k < 64; ++k) {
            float hk = r[k];
            #pragma unroll
            for (int c = 0; c < 64; ++c) acc[c] = fmaf(hk, W[k * 64 + c], acc[c]);
        }
    }
    __syncthreads();
    int node = base + t;
    bool valid = node < NN;
    #pragma unroll
    for (int c = 0; c < 64; ++c) tile[t * 65 + c] = valid ? acc[c] : 0.f;
    __syncthreads();
    for (int i = t; i < 2048; i += 128) {
        int row = i >> 4, c4 = (i & 15) << 2;
        int n2 = base + row;
        if (n2 < NN) {
            const float* p = &tile[row * 65 + c4];
            float4 v = {p[0], p[1], p[2], p[3]};
            if (POST == 1) { v.x = lrelu(v.x); v.y = lrelu(v.y); v.z = lrelu(v.z); v.w = lrelu(v.w); }
            *(float4*)(out + (size_t)n2 * 64 + c4) = v;
        }
    }
    if (POST == 0) {
        int c = t & 63, g = t >> 6;
        float s = 0.f, q = 0.f;
        for (int rr = 0; rr < 64; ++rr) {
            float v = tile[(g * 64 + rr) * 65 + c];
            s += v; q += v * v;
        }
        atomicAdd(&statsOut[c], s);
        atomicAdd(&statsOut[64 + c], q);
    }
}

// ---- elementwise x = lrelu(bn(h)) using stats
__global__ __launch_bounds__(256) void k_bn(
    const float* __restrict__ in, const float* __restrict__ stats,
    const float* __restrict__ g, const float* __restrict__ b,
    float* __restrict__ out)
{
    int tid = blockIdx.x * 256 + threadIdx.x;
    for (int i = tid; i < NN * 16; i += gridDim.x * 256) {
        int c4 = (i & 15) << 2;
        float4 v = ((const float4*)in)[i];
        float o[4] = {v.x, v.y, v.z, v.w};
        #pragma unroll
        for (int j = 0; j < 4; ++j) {
            int c = c4 + j;
            float m = stats[c] * (1.f / NN);
            float vv = stats[64 + c] * (1.f / NN) - m * m;
            float s = g[c] * rsqrtf(vv + BN_EPS);
            o[j] = lrelu(fmaf(o[j] - m, s, b[c]));
        }
        float4 r = {o[0], o[1], o[2], o[3]};
        ((float4*)out)[i] = r;
    }
}

__global__ __launch_bounds__(256) void k_pool(
    const float* __restrict__ x, const int* __restrict__ batch,
    float* __restrict__ pool)
{
    int lane = threadIdx.x & 63;
    int wid = (blockIdx.x * 256 + threadIdx.x) >> 6;
    int nw = (gridDim.x * 256) >> 6;
    for (int n = wid; n < NN; n += nw) {
        int gi = batch[n];
        atomicAdd(&pool[(size_t)gi * 64 + lane], x[(size_t)n * 64 + lane]);
    }
}

// ---- [N,128]@[128,128]+b with stats. MODE0: input = concat(x, pool[batch]).
template<int MODE>
__global__ __launch_bounds__(128) void k_cmm(
    const float* __restrict__ inA, const float* __restrict__ pool,
    const int* __restrict__ batch, const float* __restrict__ statsIn,
    const float* __restrict__ gIn, const float* __restrict__ bIn,
    const float* __restrict__ W, const float* __restrict__ bias,
    float* __restrict__ out, float* __restrict__ statsOut)
{
    __shared__ float tile[64 * 129];
    __shared__ float sc[128], sh[128];
    int t = threadIdx.x;
    int base = blockIdx.x * 64;
    if (MODE == 1) {
        float m = statsIn[t] * (1.f / NN);
        float v = statsIn[128 + t] * (1.f / NN) - m * m;
        float s = gIn[t] * rsqrtf(v + BN_EPS);
        sc[t] = s; sh[t] = bIn[t] - m * s;
        __syncthreads();
    }
    for (int i = t; i < 64 * 32; i += 128) {
        int row = i >> 5, c4 = (i & 31) << 2;
        int node = base + row;
        float4 v = {0.f, 0.f, 0.f, 0.f};
        if (node < NN) {
            if (MODE == 0) {
                if (c4 < 64) v = *(const float4*)(inA + (size_t)node * 64 + c4);
                else         v = *(const float4*)(pool + (size_t)batch[node] * 64 + (c4 - 64));
            } else {
                v = *(const float4*)(inA + (size_t)node * 128 + c4);
                v.x = lrelu(fmaf(v.x, sc[c4 + 0], sh[c4 + 0]));
                v.y = lrelu(fmaf(v.y, sc[c4 + 1], sh[c4 + 1]));
                v.z = lrelu(fmaf(v.z, sc[c4 + 2], sh[c4 + 2]));
                v.w = lrelu(fmaf(v.w, sc[c4 + 3], sh[c4 + 3]));
            }
        }
        float* p = &tile[row * 129 + c4];
        p[0] = v.x; p[1] = v.y; p[2] = v.z; p[3] = v.w;
    }
    __syncthreads();
    int lane = t & 63, half = t >> 6;
    float acc[64];
    #pragma unroll
    for (int c = 0; c < 64; ++c) acc[c] = bias[half * 64 + c];
    {
        const float* r = &tile[lane * 129];
        for (int k = 0; k < 128; ++k) {
            float hk = r[k];
            #pragma unroll
            for (int c = 0; c < 64; ++c) acc[c] = fmaf(hk, W[k * 128 + half * 64 + c], acc[c]);
        }
    }
    __syncthreads();
    int node = base + lane;
    bool valid = node < NN;
    #pragma unroll
    for (int c = 0; c < 64; ++c) tile[lane * 129 + half * 64 + c] = valid ? acc[c] : 0.f;
    __syncthreads();
    for (int i = t; i < 64 * 32; i += 128) {
        int row = i >> 5, c4 = (i & 31) << 2;
        int n2 = base + row;
        if (n2 < NN) {
            const float* p = &tile[row * 129 + c4];
            float4 v = {p[0], p[1], p[2], p[3]};
            *(float4*)(out + (size_t)n2 * 128 + c4) = v;
        }
    }
    {
        float s = 0.f, q = 0.f;
        for (int rr = 0; rr < 64; ++rr) {
            float v = tile[rr * 129 + t];
            s += v; q += v * v;
        }
        atomicAdd(&statsOut[t], s);
        atomicAdd(&statsOut[128 + t], q);
    }
}

// ---- out[n] = lrelu(bn(h128[n])) . cW3 + cb3
__global__ __launch_bounds__(256) void k_out(
    const float* __restrict__ h, const float* __restrict__ stats,
    const float* __restrict__ g, const float* __restrict__ b,
    const float* __restrict__ W3, const float* __restrict__ b3,
    float* __restrict__ outv)
{
    int lane = threadIdx.x & 63;
    int wid = (blockIdx.x * 256 + threadIdx.x) >> 6;
    int nw = (gridDim.x * 256) >> 6;
    float m0 = stats[lane] * (1.f / NN);
    float v0 = stats[128 + lane] * (1.f / NN) - m0 * m0;
    float s0 = g[lane] * rsqrtf(v0 + BN_EPS);
    float h0 = b[lane] - m0 * s0;
    float m1 = stats[64 + lane] * (1.f / NN);
    float v1 = stats[128 + 64 + lane] * (1.f / NN) - m1 * m1;
    float s1 = g[64 + lane] * rsqrtf(v1 + BN_EPS);
    float h1 = b[64 + lane] - m1 * s1;
    float w0 = W3[lane], w1 = W3[64 + lane];
    float bb = b3[0];
    for (int n = wid; n < NN; n += nw) {
        float a = h[(size_t)n * 128 + lane];
        float c = h[(size_t)n * 128 + 64 + lane];
        a = lrelu(fmaf(a, s0, h0));
        c = lrelu(fmaf(c, s1, h1));
        float p = a * w0 + c * w1;
        p += __shfl_xor(p, 32);
        p += __shfl_xor(p, 16);
        p += __shfl_xor(p, 8);
        p += __shfl_xor(p, 4);
        p += __shfl_xor(p, 2);
        p += __shfl_xor(p, 1);
        if (lane == 0) outv[n] = p + bb;
    }
}

extern "C" void kernel_launch(void* const* d_in, const int* in_sizes, int n_in,
                              void* d_out, int out_size, void* d_ws, size_t ws_size,
                              hipStream_t stream)
{
    const float* x0   = (const float*)d_in[0];
    const float* ea   = (const float*)d_in[1];
    const float* leW  = (const float*)d_in[2];
    const float* leb  = (const float*)d_in[3];
    const float* W1   = (const float*)d_in[4];
    const float* b1   = (const float*)d_in[5];
    const float* g1   = (const float*)d_in[6];
    const float* bb1  = (const float*)d_in[7];
    const float* W2   = (const float*)d_in[8];
    const float* b2   = (const float*)d_in[9];
    const float* eps  = (const float*)d_in[10];
    const float* og   = (const float*)d_in[11];
    const float* ob   = (const float*)d_in[12];
    const float* cW1  = (const float*)d_in[13];
    const float* cb1  = (const float*)d_in[14];
    const float* cg1  = (const float*)d_in[15];
    const float* cbb1 = (const float*)d_in[16];
    const float* cW2  = (const float*)d_in[17];
    const float* cb2  = (const float*)d_in[18];
    const float* cg2  = (const float*)d_in[19];
    const float* cbb2 = (const float*)d_in[20];
    const float* cW3  = (const float*)d_in[21];
    const float* cb3  = (const float*)d_in[22];
    const int* ei     = (const int*)d_in[23];
    const int* batch  = (const int*)d_in[24];
    const int* src = ei;
    const int* dst = ei + NE;

    // ---- workspace layout (4-byte units). ea_s aliases h128 (disjoint lifetimes).
    float* xbuf   = (float*)d_ws;                      // NN*64
    float* hbuf   = xbuf + (size_t)NN * 64;            // NN*64
    float* eas    = hbuf + (size_t)NN * 64;            // NE*16 (live: layers)
    float* h128   = eas;                               // NN*128 (live: head) — alias
    float* pool   = eas + (size_t)NE * 16;             // NG*64
    float* cstats = pool + (size_t)NG * 64;            // 512
    float* stats  = cstats + 512;                      // 768 (3 x 256)
    int*   cnt    = (int*)(stats + 768);               // NN
    int*   off    = cnt + NN;                          // NN+1 (+pad)
    int*   cur    = off + NN + 4;                      // NN
    int*   bsum   = cur + NN;                          // 256
    int*   boff   = bsum + 256;                        // 256
    int*   srcs   = boff + 256;                        // NE
    int*   dsts   = srcs + NE;                         // NE
    int*   perm   = dsts + NE;                         // NE
    float* outp   = (float*)d_out;

    int zeroN = NG * 64 + 512 + 768 + NN;  // pool..cnt contiguous

    int mmGrid = (NN + 127) / 128;       // 391
    int cGrid  = (NN + 63) / 64;         // 782
    int sGrid  = (NE / CH + 3) / 4;      // 6250

    // ---- CSR build + edge-attr pre-sort (once; reused by all 3 layers)
    k_prep<<<512, 256, 0, stream>>>((int*)pool, zeroN);
    k_hist<<<1024, 256, 0, stream>>>(dst, cnt);
    k_scanA<<<NB_SCAN, 256, 0, stream>>>(cnt, off, bsum);
    k_scanB<<<1, 256, 0, stream>>>(bsum, boff);
    k_scanC<<<NB_SCAN, 256, 0, stream>>>(cnt, off, boff, cur);
    k_scatter<<<1024, 256, 0, stream>>>(src, dst, cur, perm, srcs, dsts);
    k_gather<<<2048, 256, 0, stream>>>(ea, perm, eas);

    for (int l = 0; l < 3; ++l) {
        const float* xc = (l == 0) ? x0 : xbuf;
        float* st = stats + l * 256;
        k_init<<<1024, 256, 0, stream>>>(xc, eps, l, hbuf);
        k_aggr_s<<<sGrid, 256, 0, stream>>>(xc, eas, srcs, dsts,
                leW + l * 1024, leb + l * 64, hbuf);
        k_mm64<0, 0><<<mmGrid, 128, 0, stream>>>(hbuf, W1 + l * 4096, b1 + l * 64,
                nullptr, nullptr, nullptr, hbuf, st);
        if (l < 2) {
            k_mm64<1, 0><<<mmGrid, 128, 0, stream>>>(hbuf, W2 + l * 4096, b2 + l * 64,
                    st, g1 + l * 64, bb1 + l * 64, hbuf, st + 128);
            k_bn<<<1024, 256, 0, stream>>>(hbuf, st + 128, og + l * 64, ob + l * 64, xbuf);
        } else {
            k_mm64<1, 1><<<mmGrid, 128, 0, stream>>>(hbuf, W2 + l * 4096, b2 + l * 64,
                    st, g1 + l * 64, bb1 + l * 64, xbuf, nullptr);
        }
    }
    k_pool<<<1024, 256, 0, stream>>>(xbuf, batch, pool);
    k_cmm<0><<<cGrid, 128, 0, stream>>>(xbuf, pool, batch, nullptr, nullptr, nullptr,
                                        cW1, cb1, h128, cstats);
    k_cmm<1><<<cGrid, 128, 0, stream>>>(h128, nullptr, nullptr, cstats, cg1, cbb1,
                                        cW2, cb2, h128, cstats + 256);
    k_out<<<1024, 256, 0, stream>>>(h128, cstats + 256, cg2, cbb2, cW3, cb3, outp);
}

// Round 5
// 1019.758 us; speedup vs baseline: 1.5827x; 1.0562x over previous
//
#include <hip/hip_runtime.h>

#define NN 50000
#define NE 800000
#define NG 2000
#define BN_EPS 1e-5f
#define NB_SCAN 196  // ceil(NN/256)
#define CH 32        // edges per wave-chunk in k_aggr_s

__device__ __forceinline__ float lrelu(float v) { return v > 0.f ? v : 0.01f * v; }

// ---- zero pool+cstats+stats+cnt
__global__ __launch_bounds__(256) void k_prep(int* __restrict__ p, int n)
{
    int tid = blockIdx.x * 256 + threadIdx.x;
    for (int i = tid; i < n; i += gridDim.x * 256) p[i] = 0;
}

// ---- histogram of dst
__global__ __launch_bounds__(256) void k_hist(const int* __restrict__ dst, int* __restrict__ cnt)
{
    int tid = blockIdx.x * 256 + threadIdx.x;
    for (int e = tid; e < NE; e += gridDim.x * 256) atomicAdd(&cnt[dst[e]], 1);
}

__global__ __launch_bounds__(256) void k_scanA(const int* __restrict__ cnt,
    int* __restrict__ off, int* __restrict__ bsum)
{
    __shared__ int s[256];
    int t = threadIdx.x;
    int i = blockIdx.x * 256 + t;
    int v = (i < NN) ? cnt[i] : 0;
    s[t] = v; __syncthreads();
    #pragma unroll
    for (int d = 1; d < 256; d <<= 1) {
        int u = (t >= d) ? s[t - d] : 0;
        __syncthreads();
        s[t] += u;
        __syncthreads();
    }
    if (i < NN) off[i + 1] = s[t];
    if (t == 255) bsum[blockIdx.x] = s[255];
}

__global__ __launch_bounds__(256) void k_scanB(const int* __restrict__ bsum, int* __restrict__ boff)
{
    __shared__ int s[256];
    int t = threadIdx.x;
    int v = (t < NB_SCAN) ? bsum[t] : 0;
    s[t] = v; __syncthreads();
    #pragma unroll
    for (int d = 1; d < 256; d <<= 1) {
        int u = (t >= d) ? s[t - d] : 0;
        __syncthreads();
        s[t] += u;
        __syncthreads();
    }
    boff[t] = s[t] - v;
}

__global__ __launch_bounds__(256) void k_scanC(const int* __restrict__ cnt,
    int* __restrict__ off, const int* __restrict__ boff, int* __restrict__ cur)
{
    int i = blockIdx.x * 256 + threadIdx.x;
    if (i < NN) {
        int incl = off[i + 1] + boff[blockIdx.x];
        off[i + 1] = incl;
        cur[i] = incl - cnt[i];
    }
    if (i == 0) off[0] = 0;
}

// ---- scatter edge ids into dst-sorted order (perm + srcs + dsts)
__global__ __launch_bounds__(256) void k_scatter(const int* __restrict__ src,
    const int* __restrict__ dst, int* __restrict__ cur,
    int* __restrict__ perm, int* __restrict__ srcs, int* __restrict__ dsts)
{
    int tid = blockIdx.x * 256 + threadIdx.x;
    for (int e = tid; e < NE; e += gridDim.x * 256) {
        int d = dst[e];
        int p = atomicAdd(&cur[d], 1);
        perm[p] = e;
        srcs[p] = src[e];
        dsts[p] = d;
    }
}

// ---- gather edge_attr into dst-sorted order: ea_s[p] = ea[perm[p]]
__global__ __launch_bounds__(256) void k_gather(const float* __restrict__ ea,
    const int* __restrict__ perm, float* __restrict__ eas)
{
    int tid = blockIdx.x * 256 + threadIdx.x;
    for (int i = tid; i < NE * 16; i += gridDim.x * 256) {
        int p = i >> 4, j = i & 15;
        eas[i] = ea[(size_t)perm[p] * 16 + j];
    }
}

// ---- aggr = (1+eps[l]) * x
__global__ __launch_bounds__(256) void k_init(const float* __restrict__ x,
    const float* __restrict__ eps, int layer, float* __restrict__ aggr)
{
    int tid = blockIdx.x * 256 + threadIdx.x;
    float s = 1.f + eps[layer];
    const float4* xv = (const float4*)x;
    float4* av = (float4*)aggr;
    for (int i = tid; i < NN * 16; i += gridDim.x * 256) {
        float4 v = xv[i];
        v.x *= s; v.y *= s; v.z *= s; v.w *= s;
        av[i] = v;
    }
}

// ---- sorted-COO segment scan: wave owns CH contiguous sorted edges, lane=channel.
__global__ __launch_bounds__(256) void k_aggr_s(
    const float* __restrict__ x, const float* __restrict__ eas,
    const int* __restrict__ srcs, const int* __restrict__ dsts,
    const float* __restrict__ We, const float* __restrict__ be,
    float* __restrict__ aggr)
{
    __shared__ float ws[1024];   // transposed: ws[c*16+k] = We[k*64+c]
    __shared__ float bs[64];
    int t = threadIdx.x;
    for (int i = t; i < 1024; i += 256) {
        int c = i >> 4, k = i & 15;
        ws[i] = We[k * 64 + c];
    }
    if (t < 64) bs[t] = be[t];
    __syncthreads();
    int lane = t & 63;
    int chunk = blockIdx.x * 4 + (t >> 6);
    int c0 = chunk * CH;
    if (c0 >= NE) return;
    int c1 = c0 + CH; if (c1 > NE) c1 = NE;
    float bias = bs[lane];
    const float4* wv = (const float4*)(ws + lane * 16);
    float4 w0 = wv[0], w1 = wv[1], w2 = wv[2], w3 = wv[3];
    float acc = 0.f;
    int d = dsts[c0];
    #pragma unroll 4
    for (int p = c0; p < c1; ++p) {
        int s = srcs[p];
        const float4* ap = (const float4*)(eas + (size_t)p * 16);
        float4 a0 = ap[0], a1 = ap[1], a2 = ap[2], a3 = ap[3];
        float xs = x[(size_t)s * 64 + lane];
        float m = bias;
        m = fmaf(a0.x, w0.x, m); m = fmaf(a0.y, w0.y, m);
        m = fmaf(a0.z, w0.z, m); m = fmaf(a0.w, w0.w, m);
        m = fmaf(a1.x, w1.x, m); m = fmaf(a1.y, w1.y, m);
        m = fmaf(a1.z, w1.z, m); m = fmaf(a1.w, w1.w, m);
        m = fmaf(a2.x, w2.x, m); m = fmaf(a2.y, w2.y, m);
        m = fmaf(a2.z, w2.z, m); m = fmaf(a2.w, w2.w, m);
        m = fmaf(a3.x, w3.x, m); m = fmaf(a3.y, w3.y, m);
        m = fmaf(a3.z, w3.z, m); m = fmaf(a3.w, w3.w, m);
        m += xs;
        acc += fmaxf(m, 0.f);
        int dn = (p + 1 < c1) ? dsts[p + 1] : -1;
        if (dn != d) {
            atomicAdd(&aggr[(size_t)d * 64 + lane], acc);
            acc = 0.f;
            d = dn;
        }
    }
}

// ---- [N,64]@[64,64]+b, W in LDS (wave-uniform broadcast reads).
// 256 threads, 128 rows/block; thread = (row, col-half) -> acc[32].
template<int PRE, int POST>
__global__ __launch_bounds__(256) void k_mm64(
    const float* __restrict__ in, const float* __restrict__ W,
    const float* __restrict__ bias, const float* __restrict__ statsIn,
    const float* __restrict__ gIn, const float* __restrict__ bIn,
    float* __restrict__ out, float* __restrict__ statsOut)
{
    __shared__ float tile[128 * 65];  // 33.3 KB, bank-stride 1
    __shared__ float wl[4096];        // 16 KB: W[k][c] flat
    __shared__ float sc[64], sh[64];
    int t = threadIdx.x;
    int base = blockIdx.x * 128;
    if (PRE && t < 64) {
        float m = statsIn[t] * (1.f / NN);
        float v = statsIn[64 + t] * (1.f / NN) - m * m;
        float s = gIn[t] * rsqrtf(v + BN_EPS);
        sc[t] = s; sh[t] = bIn[t] - m * s;
    }
    for (int i = t; i < 1024; i += 256)
        ((float4*)wl)[i] = ((const float4*)W)[i];
    __syncthreads();
    for (int i = t; i < 2048; i += 256) {
        int row = i >> 4, c4 = (i & 15) << 2;
        int node = base + row;
        float4 v = {0.f, 0.f, 0.f, 0.f};
        if (node < NN) v = *(const float4*)(in + (size_t)node * 64 + c4);
        if (PRE) {
            v.x = lrelu(fmaf(v.x, sc[c4 + 0], sh[c4 + 0]));
            v.y = lrelu(fmaf(v.y, sc[c4 + 1], sh[c4 + 1]));
            v.z = lrelu(fmaf(v.z, sc[c4 + 2], sh[c4 + 2]));
            v.w = lrelu(fmaf(v.w, sc[c4 + 3], sh[c4 + 3]));
        }
        float* p = &tile[row * 65 + c4];
        p[0] = v.x; p[1] = v.y; p[2] = v.z; p[3] = v.w;
    }
    __syncthreads();
    int row = t & 127, half = t >> 7;
    float acc[32];
    #pragma unroll
    for (int j = 0; j < 32; ++j) acc[j] = bias[half * 32 + j];
    {
        const float* rp = &tile[row * 65];
        #pragma unroll 4
        for (int k = 0; k < 64; ++k) {
            float a = rp[k];
            const float4* wp = (const float4*)&wl[k * 64 + half * 32];
            #pragma unroll
            for (int q = 0; q < 8; ++q) {
                float4 w = wp[q];
                acc[q * 4 + 0] = fmaf(a, w.x, acc[q * 4 + 0]);
                acc[q * 4 + 1] = fmaf(a, w.y, acc[q * 4 + 1]);
                acc[q * 4 + 2] = fmaf(a, w.z, acc[q * 4 + 2]);
                acc[q * 4 + 3] = fmaf(a, w.w, acc[q * 4 + 3]);
            }
        }
    }
    __syncthreads();
    bool valid = (base + row) < NN;
    #pragma unroll
    for (int j = 0; j < 32; ++j)
        tile[row * 65 + half * 32 + j] = valid ? acc[j] : 0.f;
    __syncthreads();
    for (int i = t; i < 2048; i += 256) {
        int r2 = i >> 4, c4 = (i & 15) << 2;
        int n2 = base + r2;
        if (n2 < NN) {
            const float* p = &tile[r2 * 65 + c4];
            float4 v = {p[0], p[1], p[2], p[3]};
            if (POST == 1) { v.x = lrelu(v.x); v.y = lrelu(v.y); v.z = lrelu(v.z); v.w = lrelu(v.w); }
            *(float4*)(out + (size_t)n2 * 64 + c4) = v;
        }
    }
    if (POST == 0) {
        int c = t & 63, g = t >> 6;
        float s = 0.f, q = 0.f;
        for (int rr = 0; rr < 32; ++rr) {
            float v = tile[(g * 32 + rr) * 65 + c];
            s += v; q += v * v;
        }
        atomicAdd(&statsOut[c], s);
        atomicAdd(&statsOut[64 + c], q);
    }
}

// ---- elementwise x = lrelu(bn(h)) using stats
__global__ __launch_bounds__(256) void k_bn(
    const float* __restrict__ in, const float* __restrict__ stats,
    const float* __restrict__ g, const float* __restrict__ b,
    float* __restrict__ out)
{
    int tid = blockIdx.x * 256 + threadIdx.x;
    for (int i = tid; i < NN * 16; i += gridDim.x * 256) {
        int c4 = (i & 15) << 2;
        float4 v = ((const float4*)in)[i];
        float o[4] = {v.x, v.y, v.z, v.w};
        #pragma unroll
        for (int j = 0; j < 4; ++j) {
            int c = c4 + j;
            float m = stats[c] * (1.f / NN);
            float vv = stats[64 + c] * (1.f / NN) - m * m;
            float s = g[c] * rsqrtf(vv + BN_EPS);
            o[j] = lrelu(fmaf(o[j] - m, s, b[c]));
        }
        float4 r = {o[0], o[1], o[2], o[3]};
        ((float4*)out)[i] = r;
    }
}

__global__ __launch_bounds__(256) void k_pool(
    const float* __restrict__ x, const int* __restrict__ batch,
    float* __restrict__ pool)
{
    int lane = threadIdx.x & 63;
    int wid = (blockIdx.x * 256 + threadIdx.x) >> 6;
    int nw = (gridDim.x * 256) >> 6;
    for (int n = wid; n < NN; n += nw) {
        int gi = batch[n];
        atomicAdd(&pool[(size_t)gi * 64 + lane], x[(size_t)n * 64 + lane]);
    }
}

// ---- [N,128]@[128,128]+b, K processed in 2 chunks of 64, W chunk in LDS.
// 256 threads, 64 rows/block; thread = (row, col-quarter) -> acc[32].
// MODE0: input = concat(x, pool[batch]); MODE1: input = lrelu(bn(h128)).
template<int MODE>
__global__ __launch_bounds__(256) void k_cmm(
    const float* __restrict__ inA, const float* __restrict__ pool,
    const int* __restrict__ batch, const float* __restrict__ statsIn,
    const float* __restrict__ gIn, const float* __restrict__ bIn,
    const float* __restrict__ W, const float* __restrict__ bias,
    float* __restrict__ out, float* __restrict__ statsOut)
{
    __shared__ float atile[64 * 65];   // [row][kk], bank-stride 1 (16.6 KB)
    __shared__ float wreg[64 * 129];   // wl chunk [kk][c] (32 KB) / otile [row][129] alias
    __shared__ float sc[128], sh[128];
    int t = threadIdx.x;
    int base = blockIdx.x * 64;
    if (MODE == 1 && t < 128) {
        float m = statsIn[t] * (1.f / NN);
        float v = statsIn[128 + t] * (1.f / NN) - m * m;
        float s = gIn[t] * rsqrtf(v + BN_EPS);
        sc[t] = s; sh[t] = bIn[t] - m * s;
    }
    int row = t & 63, qq = t >> 6;
    float acc[32];
    #pragma unroll
    for (int j = 0; j < 32; ++j) acc[j] = bias[qq * 32 + j];
    for (int kc = 0; kc < 2; ++kc) {
        __syncthreads();
        // stage A chunk [64 rows][64 k]
        for (int i = t; i < 1024; i += 256) {
            int r = i >> 4, c4 = (i & 15) << 2;
            int node = base + r;
            float4 v = {0.f, 0.f, 0.f, 0.f};
            if (node < NN) {
                if (MODE == 0) {
                    v = (kc == 0) ? *(const float4*)(inA + (size_t)node * 64 + c4)
                                  : *(const float4*)(pool + (size_t)batch[node] * 64 + c4);
                } else {
                    int cc = kc * 64 + c4;
                    v = *(const float4*)(inA + (size_t)node * 128 + cc);
                    v.x = lrelu(fmaf(v.x, sc[cc + 0], sh[cc + 0]));
                    v.y = lrelu(fmaf(v.y, sc[cc + 1], sh[cc + 1]));
                    v.z = lrelu(fmaf(v.z, sc[cc + 2], sh[cc + 2]));
                    v.w = lrelu(fmaf(v.w, sc[cc + 3], sh[cc + 3]));
                }
            }
            float* p = &atile[r * 65 + c4];
            p[0] = v.x; p[1] = v.y; p[2] = v.z; p[3] = v.w;
        }
        // stage W chunk [64 kk][128 c] flat
        {
            const float4* wsrc = (const float4*)(W + (size_t)kc * 64 * 128);
            for (int i = t; i < 2048; i += 256)
                ((float4*)wreg)[i] = wsrc[i];
        }
        __syncthreads();
        const float* rp = &atile[row * 65];
        #pragma unroll 4
        for (int kk = 0; kk < 64; ++kk) {
            float a = rp[kk];
            const float4* wp = (const float4*)&wreg[kk * 128 + qq * 32];
            #pragma unroll
            for (int q = 0; q < 8; ++q) {
                float4 w = wp[q];
                acc[q * 4 + 0] = fmaf(a, w.x, acc[q * 4 + 0]);
                acc[q * 4 + 1] = fmaf(a, w.y, acc[q * 4 + 1]);
                acc[q * 4 + 2] = fmaf(a, w.z, acc[q * 4 + 2]);
                acc[q * 4 + 3] = fmaf(a, w.w, acc[q * 4 + 3]);
            }
        }
    }
    __syncthreads();
    // reuse wreg as output tile [64][129]
    bool valid = (base + row) < NN;
    #pragma unroll
    for (int j = 0; j < 32; ++j)
        wreg[row * 129 + qq * 32 + j] = valid ? acc[j] : 0.f;
    __syncthreads();
    for (int i = t; i < 2048; i += 256) {
        int r2 = i >> 5, c4 = (i & 31) << 2;
        int n2 = base + r2;
        if (n2 < NN) {
            const float* p = &wreg[r2 * 129 + c4];
            float4 v = {p[0], p[1], p[2], p[3]};
            *(float4*)(out + (size_t)n2 * 128 + c4) = v;
        }
    }
    {
        int c = t & 127, g = t >> 7;
        float s = 0.f, q = 0.f;
        for (int rr = 0; rr < 32; ++rr) {
            float v = wreg[(g * 32 + rr) * 129 + c];
            s += v; q += v * v;
        }
        atomicAdd(&statsOut[c], s);
        atomicAdd(&statsOut[128 + c], q);
    }
}

// ---- out[n] = lrelu(bn(h128[n])) . cW3 + cb3
__global__ __launch_bounds__(256) void k_out(
    const float* __restrict__ h, const float* __restrict__ stats,
    const float* __restrict__ g, const float* __restrict__ b,
    const float* __restrict__ W3, const float* __restrict__ b3,
    float* __restrict__ outv)
{
    int lane = threadIdx.x & 63;
    int wid = (blockIdx.x * 256 + threadIdx.x) >> 6;
    int nw = (gridDim.x * 256) >> 6;
    float m0 = stats[lane] * (1.f / NN);
    float v0 = stats[128 + lane] * (1.f / NN) - m0 * m0;
    float s0 = g[lane] * rsqrtf(v0 + BN_EPS);
    float h0 = b[lane] - m0 * s0;
    float m1 = stats[64 + lane] * (1.f / NN);
    float v1 = stats[128 + 64 + lane] * (1.f / NN) - m1 * m1;
    float s1 = g[64 + lane] * rsqrtf(v1 + BN_EPS);
    float h1 = b[64 + lane] - m1 * s1;
    float w0 = W3[lane], w1 = W3[64 + lane];
    float bb = b3[0];
    for (int n = wid; n < NN; n += nw) {
        float a = h[(size_t)n * 128 + lane];
        float c = h[(size_t)n * 128 + 64 + lane];
        a = lrelu(fmaf(a, s0, h0));
        c = lrelu(fmaf(c, s1, h1));
        float p = a * w0 + c * w1;
        p += __shfl_xor(p, 32);
        p += __shfl_xor(p, 16);
        p += __shfl_xor(p, 8);
        p += __shfl_xor(p, 4);
        p += __shfl_xor(p, 2);
        p += __shfl_xor(p, 1);
        if (lane == 0) outv[n] = p + bb;
    }
}

extern "C" void kernel_launch(void* const* d_in, const int* in_sizes, int n_in,
                              void* d_out, int out_size, void* d_ws, size_t ws_size,
                              hipStream_t stream)
{
    const float* x0   = (const float*)d_in[0];
    const float* ea   = (const float*)d_in[1];
    const float* leW  = (const float*)d_in[2];
    const float* leb  = (const float*)d_in[3];
    const float* W1   = (const float*)d_in[4];
    const float* b1   = (const float*)d_in[5];
    const float* g1   = (const float*)d_in[6];
    const float* bb1  = (const float*)d_in[7];
    const float* W2   = (const float*)d_in[8];
    const float* b2   = (const float*)d_in[9];
    const float* eps  = (const float*)d_in[10];
    const float* og   = (const float*)d_in[11];
    const float* ob   = (const float*)d_in[12];
    const float* cW1  = (const float*)d_in[13];
    const float* cb1  = (const float*)d_in[14];
    const float* cg1  = (const float*)d_in[15];
    const float* cbb1 = (const float*)d_in[16];
    const float* cW2  = (const float*)d_in[17];
    const float* cb2  = (const float*)d_in[18];
    const float* cg2  = (const float*)d_in[19];
    const float* cbb2 = (const float*)d_in[20];
    const float* cW3  = (const float*)d_in[21];
    const float* cb3  = (const float*)d_in[22];
    const int* ei     = (const int*)d_in[23];
    const int* batch  = (const int*)d_in[24];
    const int* src = ei;
    const int* dst = ei + NE;

    // ---- workspace layout (4-byte units). ea_s aliases h128 (disjoint lifetimes).
    float* xbuf   = (float*)d_ws;                      // NN*64
    float* hbuf   = xbuf + (size_t)NN * 64;            // NN*64
    float* eas    = hbuf + (size_t)NN * 64;            // NE*16 (live: layers)
    float* h128   = eas;                               // NN*128 (live: head) — alias
    float* pool   = eas + (size_t)NE * 16;             // NG*64
    float* cstats = pool + (size_t)NG * 64;            // 512
    float* stats  = cstats + 512;                      // 768 (3 x 256)
    int*   cnt    = (int*)(stats + 768);               // NN
    int*   off    = cnt + NN;                          // NN+1 (+pad)
    int*   cur    = off + NN + 4;                      // NN
    int*   bsum   = cur + NN;                          // 256
    int*   boff   = bsum + 256;                        // 256
    int*   srcs   = boff + 256;                        // NE
    int*   dsts   = srcs + NE;                         // NE
    int*   perm   = dsts + NE;                         // NE
    float* outp   = (float*)d_out;

    int zeroN = NG * 64 + 512 + 768 + NN;  // pool..cnt contiguous

    int mmGrid = (NN + 127) / 128;       // 391
    int cGrid  = (NN + 63) / 64;         // 782
    int sGrid  = (NE / CH + 3) / 4;      // 6250

    // ---- CSR build + edge-attr pre-sort (once; reused by all 3 layers)
    k_prep<<<512, 256, 0, stream>>>((int*)pool, zeroN);
    k_hist<<<1024, 256, 0, stream>>>(dst, cnt);
    k_scanA<<<NB_SCAN, 256, 0, stream>>>(cnt, off, bsum);
    k_scanB<<<1, 256, 0, stream>>>(bsum, boff);
    k_scanC<<<NB_SCAN, 256, 0, stream>>>(cnt, off, boff, cur);
    k_scatter<<<1024, 256, 0, stream>>>(src, dst, cur, perm, srcs, dsts);
    k_gather<<<2048, 256, 0, stream>>>(ea, perm, eas);

    for (int l = 0; l < 3; ++l) {
        const float* xc = (l == 0) ? x0 : xbuf;
        float* st = stats + l * 256;
        k_init<<<1024, 256, 0, stream>>>(xc, eps, l, hbuf);
        k_aggr_s<<<sGrid, 256, 0, stream>>>(xc, eas, srcs, dsts,
                leW + l * 1024, leb + l * 64, hbuf);
        k_mm64<0, 0><<<mmGrid, 256, 0, stream>>>(hbuf, W1 + l * 4096, b1 + l * 64,
                nullptr, nullptr, nullptr, hbuf, st);
        if (l < 2) {
            k_mm64<1, 0><<<mmGrid, 256, 0, stream>>>(hbuf, W2 + l * 4096, b2 + l * 64,
                    st, g1 + l * 64, bb1 + l * 64, hbuf, st + 128);
            k_bn<<<1024, 256, 0, stream>>>(hbuf, st + 128, og + l * 64, ob + l * 64, xbuf);
        } else {
            k_mm64<1, 1><<<mmGrid, 256, 0, stream>>>(hbuf, W2 + l * 4096, b2 + l * 64,
                    st, g1 + l * 64, bb1 + l * 64, xbuf, nullptr);
        }
    }
    k_pool<<<1024, 256, 0, stream>>>(xbuf, batch, pool);
    k_cmm<0><<<cGrid, 256, 0, stream>>>(xbuf, pool, batch, nullptr, nullptr, nullptr,
                                        cW1, cb1, h128, cstats);
    k_cmm<1><<<cGrid, 256, 0, stream>>>(h128, nullptr, nullptr, cstats, cg1, cbb1,
                                        cW2, cb2, h128, cstats + 256);
    k_out<<<1024, 256, 0, stream>>>(h128, cstats + 256, cg2, cbb2, cW3, cb3, outp);
}

// Round 7
// 813.333 us; speedup vs baseline: 1.9845x; 1.2538x over previous
//
#include <hip/hip_runtime.h>

#define NN 50000
#define NE 800000
#define NG 2000
#define BN_EPS 1e-5f
#define NB_SCAN 196  // ceil(NN/256)
#define CH 32        // edges per wave-chunk in k_aggr_s

typedef __attribute__((ext_vector_type(8))) short bf16x8;
typedef __attribute__((ext_vector_type(4))) float f32x4;

__device__ __forceinline__ float lrelu(float v) { return v > 0.f ? v : 0.01f * v; }

__device__ __forceinline__ unsigned short f2bf(float x) {
    union { float f; unsigned u; } v; v.f = x;
    unsigned r = v.u + 0x7FFF + ((v.u >> 16) & 1);
    return (unsigned short)(r >> 16);
}
__device__ __forceinline__ float bf2f(unsigned short h) {
    union { unsigned u; float f; } v; v.u = ((unsigned)h) << 16;
    return v.f;
}

// ---- zero pool+cstats+stats+cnt
__global__ __launch_bounds__(256) void k_prep(int* __restrict__ p, int n)
{
    int tid = blockIdx.x * 256 + threadIdx.x;
    for (int i = tid; i < n; i += gridDim.x * 256) p[i] = 0;
}

// ---- convert + transpose GEMM weights to split bf16 (hi+lo) [N][K]
__global__ __launch_bounds__(256) void k_wcvt(
    const float* __restrict__ W1, const float* __restrict__ W2,
    const float* __restrict__ cW1, const float* __restrict__ cW2,
    unsigned short* __restrict__ w1h, unsigned short* __restrict__ w1l,
    unsigned short* __restrict__ w2h, unsigned short* __restrict__ w2l,
    unsigned short* __restrict__ cw1h, unsigned short* __restrict__ cw1l,
    unsigned short* __restrict__ cw2h, unsigned short* __restrict__ cw2l)
{
    int b = blockIdx.x, t = threadIdx.x;
    if (b < 6) {
        const float* s = (b < 3) ? (W1 + b * 4096) : (W2 + (b - 3) * 4096);
        unsigned short* dh = (b < 3) ? (w1h + b * 4096) : (w2h + (b - 3) * 4096);
        unsigned short* dl = (b < 3) ? (w1l + b * 4096) : (w2l + (b - 3) * 4096);
        for (int i = t; i < 4096; i += 256) {
            int k = i >> 6, n = i & 63;
            float v = s[i];
            unsigned short h = f2bf(v);
            dh[n * 64 + k] = h;
            dl[n * 64 + k] = f2bf(v - bf2f(h));
        }
    } else {
        const float* s = (b == 6) ? cW1 : cW2;
        unsigned short* dh = (b == 6) ? cw1h : cw2h;
        unsigned short* dl = (b == 6) ? cw1l : cw2l;
        for (int i = t; i < 16384; i += 256) {
            int k = i >> 7, n = i & 127;
            float v = s[i];
            unsigned short h = f2bf(v);
            dh[n * 128 + k] = h;
            dl[n * 128 + k] = f2bf(v - bf2f(h));
        }
    }
}

// ---- histogram of dst
__global__ __launch_bounds__(256) void k_hist(const int* __restrict__ dst, int* __restrict__ cnt)
{
    int tid = blockIdx.x * 256 + threadIdx.x;
    for (int e = tid; e < NE; e += gridDim.x * 256) atomicAdd(&cnt[dst[e]], 1);
}

__global__ __launch_bounds__(256) void k_scanA(const int* __restrict__ cnt,
    int* __restrict__ off, int* __restrict__ bsum)
{
    __shared__ int s[256];
    int t = threadIdx.x;
    int i = blockIdx.x * 256 + t;
    int v = (i < NN) ? cnt[i] : 0;
    s[t] = v; __syncthreads();
    #pragma unroll
    for (int d = 1; d < 256; d <<= 1) {
        int u = (t >= d) ? s[t - d] : 0;
        __syncthreads();
        s[t] += u;
        __syncthreads();
    }
    if (i < NN) off[i + 1] = s[t];
    if (t == 255) bsum[blockIdx.x] = s[255];
}

__global__ __launch_bounds__(256) void k_scanB(const int* __restrict__ bsum, int* __restrict__ boff)
{
    __shared__ int s[256];
    int t = threadIdx.x;
    int v = (t < NB_SCAN) ? bsum[t] : 0;
    s[t] = v; __syncthreads();
    #pragma unroll
    for (int d = 1; d < 256; d <<= 1) {
        int u = (t >= d) ? s[t - d] : 0;
        __syncthreads();
        s[t] += u;
        __syncthreads();
    }
    boff[t] = s[t] - v;
}

__global__ __launch_bounds__(256) void k_scanC(const int* __restrict__ cnt,
    int* __restrict__ off, const int* __restrict__ boff, int* __restrict__ cur)
{
    int i = blockIdx.x * 256 + threadIdx.x;
    if (i < NN) {
        int incl = off[i + 1] + boff[blockIdx.x];
        off[i + 1] = incl;
        cur[i] = incl - cnt[i];
    }
    if (i == 0) off[0] = 0;
}

// ---- scatter edge ids into dst-sorted order (perm + srcs + dsts)
__global__ __launch_bounds__(256) void k_scatter(const int* __restrict__ src,
    const int* __restrict__ dst, int* __restrict__ cur,
    int* __restrict__ perm, int* __restrict__ srcs, int* __restrict__ dsts)
{
    int tid = blockIdx.x * 256 + threadIdx.x;
    for (int e = tid; e < NE; e += gridDim.x * 256) {
        int d = dst[e];
        int p = atomicAdd(&cur[d], 1);
        perm[p] = e;
        srcs[p] = src[e];
        dsts[p] = d;
    }
}

// ---- gather edge_attr into dst-sorted order
__global__ __launch_bounds__(256) void k_gather(const float* __restrict__ ea,
    const int* __restrict__ perm, float* __restrict__ eas)
{
    int tid = blockIdx.x * 256 + threadIdx.x;
    for (int i = tid; i < NE * 16; i += gridDim.x * 256) {
        int p = i >> 4, j = i & 15;
        eas[i] = ea[(size_t)perm[p] * 16 + j];
    }
}

// ---- aggr = (1+eps[l]) * x
__global__ __launch_bounds__(256) void k_init(const float* __restrict__ x,
    const float* __restrict__ eps, int layer, float* __restrict__ aggr)
{
    int tid = blockIdx.x * 256 + threadIdx.x;
    float s = 1.f + eps[layer];
    const float4* xv = (const float4*)x;
    float4* av = (float4*)aggr;
    for (int i = tid; i < NN * 16; i += gridDim.x * 256) {
        float4 v = xv[i];
        v.x *= s; v.y *= s; v.z *= s; v.w *= s;
        av[i] = v;
    }
}

// ---- sorted-COO segment scan: wave owns CH contiguous sorted edges, lane=channel.
__global__ __launch_bounds__(256) void k_aggr_s(
    const float* __restrict__ x, const float* __restrict__ eas,
    const int* __restrict__ srcs, const int* __restrict__ dsts,
    const float* __restrict__ We, const float* __restrict__ be,
    float* __restrict__ aggr)
{
    __shared__ float ws[1024];   // transposed: ws[c*16+k] = We[k*64+c]
    __shared__ float bs[64];
    int t = threadIdx.x;
    for (int i = t; i < 1024; i += 256) {
        int c = i >> 4, k = i & 15;
        ws[i] = We[k * 64 + c];
    }
    if (t < 64) bs[t] = be[t];
    __syncthreads();
    int lane = t & 63;
    int chunk = blockIdx.x * 4 + (t >> 6);
    int c0 = chunk * CH;
    if (c0 >= NE) return;
    int c1 = c0 + CH; if (c1 > NE) c1 = NE;
    float bias = bs[lane];
    const float4* wv = (const float4*)(ws + lane * 16);
    float4 w0 = wv[0], w1 = wv[1], w2 = wv[2], w3 = wv[3];
    float acc = 0.f;
    int d = dsts[c0];
    #pragma unroll 4
    for (int p = c0; p < c1; ++p) {
        int s = srcs[p];
        const float4* ap = (const float4*)(eas + (size_t)p * 16);
        float4 a0 = ap[0], a1 = ap[1], a2 = ap[2], a3 = ap[3];
        float xs = x[(size_t)s * 64 + lane];
        float m = bias;
        m = fmaf(a0.x, w0.x, m); m = fmaf(a0.y, w0.y, m);
        m = fmaf(a0.z, w0.z, m); m = fmaf(a0.w, w0.w, m);
        m = fmaf(a1.x, w1.x, m); m = fmaf(a1.y, w1.y, m);
        m = fmaf(a1.z, w1.z, m); m = fmaf(a1.w, w1.w, m);
        m = fmaf(a2.x, w2.x, m); m = fmaf(a2.y, w2.y, m);
        m = fmaf(a2.z, w2.z, m); m = fmaf(a2.w, w2.w, m);
        m = fmaf(a3.x, w3.x, m); m = fmaf(a3.y, w3.y, m);
        m = fmaf(a3.z, w3.z, m); m = fmaf(a3.w, w3.w, m);
        m += xs;
        acc += fmaxf(m, 0.f);
        int dn = (p + 1 < c1) ? dsts[p + 1] : -1;
        if (dn != d) {
            atomicAdd(&aggr[(size_t)d * 64 + lane], acc);
            acc = 0.f;
            d = dn;
        }
    }
}

// ---- split-bf16 MFMA [N,64]@Wt+b: acc = Ah*Wh + Al*Wh + Ah*Wl (fp32-grade).
template<int PRE, int POST>
__global__ __launch_bounds__(256) void k_mm64_f(
    const float* __restrict__ in,
    const unsigned short* __restrict__ Wh, const unsigned short* __restrict__ Wl,
    const float* __restrict__ bias, const float* __restrict__ statsIn,
    const float* __restrict__ gIn, const float* __restrict__ bIn,
    float* __restrict__ out, float* __restrict__ statsOut)
{
    __shared__ unsigned short Ash[64 * 64], Asl[64 * 64];  // [row][k], 16B chunk swizzle cb^(row&7)
    __shared__ unsigned short Bsh[64 * 64], Bsl[64 * 64];  // [n][k], same swizzle
    __shared__ float sc[64], sh[64];
    __shared__ float red[4 * 128];
    int t = threadIdx.x;
    int base = blockIdx.x * 64;
    if (PRE && t < 64) {
        float m = statsIn[t] * (1.f / NN);
        float v = statsIn[64 + t] * (1.f / NN) - m * m;
        float s = gIn[t] * rsqrtf(v + BN_EPS);
        sc[t] = s; sh[t] = bIn[t] - m * s;
    }
    for (int i = t; i < 512; i += 256) {
        int n = i >> 3, cb = i & 7;
        ((uint4*)Bsh)[n * 8 + (cb ^ (n & 7))] = ((const uint4*)Wh)[i];
        ((uint4*)Bsl)[n * 8 + (cb ^ (n & 7))] = ((const uint4*)Wl)[i];
    }
    __syncthreads();
    for (int i = t; i < 512; i += 256) {
        int row = i >> 3, cb = i & 7;
        int node = base + row;
        float v[8] = {0.f, 0.f, 0.f, 0.f, 0.f, 0.f, 0.f, 0.f};
        if (node < NN) {
            float4 u0 = *(const float4*)(in + (size_t)node * 64 + cb * 8);
            float4 u1 = *(const float4*)(in + (size_t)node * 64 + cb * 8 + 4);
            v[0] = u0.x; v[1] = u0.y; v[2] = u0.z; v[3] = u0.w;
            v[4] = u1.x; v[5] = u1.y; v[6] = u1.z; v[7] = u1.w;
            if (PRE) {
                #pragma unroll
                for (int j = 0; j < 8; ++j) {
                    int c = cb * 8 + j;
                    v[j] = lrelu(fmaf(v[j], sc[c], sh[c]));
                }
            }
        }
        unsigned hw[4], lw[4];
        #pragma unroll
        for (int j = 0; j < 4; ++j) {
            unsigned short h0 = f2bf(v[2 * j]), h1 = f2bf(v[2 * j + 1]);
            unsigned short l0 = f2bf(v[2 * j] - bf2f(h0)), l1 = f2bf(v[2 * j + 1] - bf2f(h1));
            hw[j] = (unsigned)h0 | ((unsigned)h1 << 16);
            lw[j] = (unsigned)l0 | ((unsigned)l1 << 16);
        }
        uint4 rh = { hw[0], hw[1], hw[2], hw[3] };
        uint4 rl = { lw[0], lw[1], lw[2], lw[3] };
        int idx = row * 8 + (cb ^ (row & 7));
        ((uint4*)Ash)[idx] = rh;
        ((uint4*)Asl)[idx] = rl;
    }
    __syncthreads();

    int w = t >> 6, l = t & 63;
    int ar = l & 15, kg = l >> 4;
    bf16x8 afh[2], afl[2];
    #pragma unroll
    for (int kt = 0; kt < 2; ++kt) {
        int row = w * 16 + ar, cb = kt * 4 + kg;
        int idx = row * 8 + (cb ^ (row & 7));
        afh[kt] = ((const bf16x8*)Ash)[idx];
        afl[kt] = ((const bf16x8*)Asl)[idx];
    }
    f32x4 acc[4];
    #pragma unroll
    for (int nt = 0; nt < 4; ++nt) { acc[nt][0] = 0.f; acc[nt][1] = 0.f; acc[nt][2] = 0.f; acc[nt][3] = 0.f; }
    #pragma unroll
    for (int nt = 0; nt < 4; ++nt) {
        #pragma unroll
        for (int kt = 0; kt < 2; ++kt) {
            int n = nt * 16 + ar, cb = kt * 4 + kg;
            int idx = n * 8 + (cb ^ (n & 7));
            bf16x8 bfh = ((const bf16x8*)Bsh)[idx];
            bf16x8 bfl = ((const bf16x8*)Bsl)[idx];
            acc[nt] = __builtin_amdgcn_mfma_f32_16x16x32_bf16(afh[kt], bfh, acc[nt], 0, 0, 0);
            acc[nt] = __builtin_amdgcn_mfma_f32_16x16x32_bf16(afl[kt], bfh, acc[nt], 0, 0, 0);
            acc[nt] = __builtin_amdgcn_mfma_f32_16x16x32_bf16(afh[kt], bfl, acc[nt], 0, 0, 0);
        }
    }
    int rb = base + w * 16 + kg * 4;
    #pragma unroll
    for (int nt = 0; nt < 4; ++nt) {
        int col = nt * 16 + ar;
        float bv = bias[col];
        float s = 0.f, q = 0.f;
        #pragma unroll
        for (int r = 0; r < 4; ++r) {
            int node = rb + r;
            float d = acc[nt][r] + bv;
            if (POST == 1) d = lrelu(d);
            if (node < NN) out[(size_t)node * 64 + col] = d;
            if (POST == 0) {
                d = (node < NN) ? d : 0.f;
                s += d; q += d * d;
            }
        }
        if (POST == 0) {
            s += __shfl_xor(s, 16); s += __shfl_xor(s, 32);
            q += __shfl_xor(q, 16); q += __shfl_xor(q, 32);
            if (kg == 0) { red[w * 128 + col] = s; red[w * 128 + 64 + col] = q; }
        }
    }
    if (POST == 0) {
        __syncthreads();
        if (t < 128) {
            int c = t & 63, which = t >> 6;
            float v = red[0 * 128 + which * 64 + c] + red[1 * 128 + which * 64 + c]
                    + red[2 * 128 + which * 64 + c] + red[3 * 128 + which * 64 + c];
            atomicAdd(&statsOut[which * 64 + c], v);
        }
    }
}

// ---- split-bf16 MFMA [N,128]@Wt+b, 64-col blocks (blockIdx.x = row_blk*2 + col_blk).
template<int MODE>
__global__ __launch_bounds__(256) void k_cmm_f(
    const float* __restrict__ inA, const float* __restrict__ pool,
    const int* __restrict__ batch, const float* __restrict__ statsIn,
    const float* __restrict__ gIn, const float* __restrict__ bIn,
    const unsigned short* __restrict__ Wh, const unsigned short* __restrict__ Wl,
    const float* __restrict__ bias,
    float* __restrict__ out, float* __restrict__ statsOut)
{
    __shared__ unsigned short Ash[64 * 128], Asl[64 * 128];  // [row][k] swizzled
    __shared__ unsigned short Bsh[64 * 128], Bsl[64 * 128];  // [nloc][k] swizzled
    __shared__ float sc[128], sh[128];
    __shared__ float red[4 * 128];
    int t = threadIdx.x;
    int base = (blockIdx.x >> 1) * 64;
    int ncol0 = (blockIdx.x & 1) * 64;
    if (MODE == 1 && t < 128) {
        float m = statsIn[t] * (1.f / NN);
        float v = statsIn[128 + t] * (1.f / NN) - m * m;
        float s = gIn[t] * rsqrtf(v + BN_EPS);
        sc[t] = s; sh[t] = bIn[t] - m * s;
    }
    for (int i = t; i < 1024; i += 256) {
        int n = i >> 4, cb = i & 15;
        int idx = n * 16 + (cb ^ (n & 7));
        ((uint4*)Bsh)[idx] = ((const uint4*)Wh)[(ncol0 + n) * 16 + cb];
        ((uint4*)Bsl)[idx] = ((const uint4*)Wl)[(ncol0 + n) * 16 + cb];
    }
    __syncthreads();
    for (int i = t; i < 1024; i += 256) {
        int row = i >> 4, cb = i & 15;
        int node = base + row;
        float v[8] = {0.f, 0.f, 0.f, 0.f, 0.f, 0.f, 0.f, 0.f};
        if (node < NN) {
            const float* sp;
            if (MODE == 0) {
                sp = (cb < 8) ? (inA + (size_t)node * 64 + cb * 8)
                              : (pool + (size_t)batch[node] * 64 + (cb - 8) * 8);
            } else {
                sp = inA + (size_t)node * 128 + cb * 8;
            }
            float4 u0 = *(const float4*)sp;
            float4 u1 = *(const float4*)(sp + 4);
            v[0] = u0.x; v[1] = u0.y; v[2] = u0.z; v[3] = u0.w;
            v[4] = u1.x; v[5] = u1.y; v[6] = u1.z; v[7] = u1.w;
            if (MODE == 1) {
                #pragma unroll
                for (int j = 0; j < 8; ++j) {
                    int c = cb * 8 + j;
                    v[j] = lrelu(fmaf(v[j], sc[c], sh[c]));
                }
            }
        }
        unsigned hw[4], lw[4];
        #pragma unroll
        for (int j = 0; j < 4; ++j) {
            unsigned short h0 = f2bf(v[2 * j]), h1 = f2bf(v[2 * j + 1]);
            unsigned short l0 = f2bf(v[2 * j] - bf2f(h0)), l1 = f2bf(v[2 * j + 1] - bf2f(h1));
            hw[j] = (unsigned)h0 | ((unsigned)h1 << 16);
            lw[j] = (unsigned)l0 | ((unsigned)l1 << 16);
        }
        uint4 rh = { hw[0], hw[1], hw[2], hw[3] };
        uint4 rl = { lw[0], lw[1], lw[2], lw[3] };
        int idx = row * 16 + (cb ^ (row & 7));
        ((uint4*)Ash)[idx] = rh;
        ((uint4*)Asl)[idx] = rl;
    }
    __syncthreads();

    int w = t >> 6, l = t & 63;
    int ar = l & 15, kg = l >> 4;
    bf16x8 afh[4], afl[4];
    #pragma unroll
    for (int kt = 0; kt < 4; ++kt) {
        int row = w * 16 + ar, cb = kt * 4 + kg;
        int idx = row * 16 + (cb ^ (row & 7));
        afh[kt] = ((const bf16x8*)Ash)[idx];
        afl[kt] = ((const bf16x8*)Asl)[idx];
    }
    f32x4 acc[4];
    #pragma unroll
    for (int nt = 0; nt < 4; ++nt) { acc[nt][0] = 0.f; acc[nt][1] = 0.f; acc[nt][2] = 0.f; acc[nt][3] = 0.f; }
    #pragma unroll
    for (int nt = 0; nt < 4; ++nt) {
        #pragma unroll
        for (int kt = 0; kt < 4; ++kt) {
            int n = nt * 16 + ar, cb = kt * 4 + kg;
            int idx = n * 16 + (cb ^ (n & 7));
            bf16x8 bfh = ((const bf16x8*)Bsh)[idx];
            bf16x8 bfl = ((const bf16x8*)Bsl)[idx];
            acc[nt] = __builtin_amdgcn_mfma_f32_16x16x32_bf16(afh[kt], bfh, acc[nt], 0, 0, 0);
            acc[nt] = __builtin_amdgcn_mfma_f32_16x16x32_bf16(afl[kt], bfh, acc[nt], 0, 0, 0);
            acc[nt] = __builtin_amdgcn_mfma_f32_16x16x32_bf16(afh[kt], bfl, acc[nt], 0, 0, 0);
        }
    }
    int rb = base + w * 16 + kg * 4;
    #pragma unroll
    for (int nt = 0; nt < 4; ++nt) {
        int colg = ncol0 + nt * 16 + ar;
        float bv = bias[colg];
        float s = 0.f, q = 0.f;
        #pragma unroll
        for (int r = 0; r < 4; ++r) {
            int node = rb + r;
            float d = acc[nt][r] + bv;
            if (node < NN) out[(size_t)node * 128 + colg] = d;
            d = (node < NN) ? d : 0.f;
            s += d; q += d * d;
        }
        s += __shfl_xor(s, 16); s += __shfl_xor(s, 32);
        q += __shfl_xor(q, 16); q += __shfl_xor(q, 32);
        int col = nt * 16 + ar;
        if (kg == 0) { red[w * 128 + col] = s; red[w * 128 + 64 + col] = q; }
    }
    __syncthreads();
    if (t < 128) {
        int c = t & 63, which = t >> 6;
        float v = red[0 * 128 + which * 64 + c] + red[1 * 128 + which * 64 + c]
                + red[2 * 128 + which * 64 + c] + red[3 * 128 + which * 64 + c];
        atomicAdd(&statsOut[which * 128 + ncol0 + c], v);
    }
}

// ---- elementwise x = lrelu(bn(h)) using stats
__global__ __launch_bounds__(256) void k_bn(
    const float* __restrict__ in, const float* __restrict__ stats,
    const float* __restrict__ g, const float* __restrict__ b,
    float* __restrict__ out)
{
    int tid = blockIdx.x * 256 + threadIdx.x;
    for (int i = tid; i < NN * 16; i += gridDim.x * 256) {
        int c4 = (i & 15) << 2;
        float4 v = ((const float4*)in)[i];
        float o[4] = {v.x, v.y, v.z, v.w};
        #pragma unroll
        for (int j = 0; j < 4; ++j) {
            int c = c4 + j;
            float m = stats[c] * (1.f / NN);
            float vv = stats[64 + c] * (1.f / NN) - m * m;
            float s = g[c] * rsqrtf(vv + BN_EPS);
            o[j] = lrelu(fmaf(o[j] - m, s, b[c]));
        }
        float4 r = {o[0], o[1], o[2], o[3]};
        ((float4*)out)[i] = r;
    }
}

__global__ __launch_bounds__(256) void k_pool(
    const float* __restrict__ x, const int* __restrict__ batch,
    float* __restrict__ pool)
{
    int lane = threadIdx.x & 63;
    int wid = (blockIdx.x * 256 + threadIdx.x) >> 6;
    int nw = (gridDim.x * 256) >> 6;
    for (int n = wid; n < NN; n += nw) {
        int gi = batch[n];
        atomicAdd(&pool[(size_t)gi * 64 + lane], x[(size_t)n * 64 + lane]);
    }
}

// ---- out[n] = lrelu(bn(h128[n])) . cW3 + cb3
__global__ __launch_bounds__(256) void k_out(
    const float* __restrict__ h, const float* __restrict__ stats,
    const float* __restrict__ g, const float* __restrict__ b,
    const float* __restrict__ W3, const float* __restrict__ b3,
    float* __restrict__ outv)
{
    int lane = threadIdx.x & 63;
    int wid = (blockIdx.x * 256 + threadIdx.x) >> 6;
    int nw = (gridDim.x * 256) >> 6;
    float m0 = stats[lane] * (1.f / NN);
    float v0 = stats[128 + lane] * (1.f / NN) - m0 * m0;
    float s0 = g[lane] * rsqrtf(v0 + BN_EPS);
    float h0 = b[lane] - m0 * s0;
    float m1 = stats[64 + lane] * (1.f / NN);
    float v1 = stats[128 + 64 + lane] * (1.f / NN) - m1 * m1;
    float s1 = g[64 + lane] * rsqrtf(v1 + BN_EPS);
    float h1 = b[64 + lane] - m1 * s1;
    float w0 = W3[lane], w1 = W3[64 + lane];
    float bb = b3[0];
    for (int n = wid; n < NN; n += nw) {
        float a = h[(size_t)n * 128 + lane];
        float c = h[(size_t)n * 128 + 64 + lane];
        a = lrelu(fmaf(a, s0, h0));
        c = lrelu(fmaf(c, s1, h1));
        float p = a * w0 + c * w1;
        p += __shfl_xor(p, 32);
        p += __shfl_xor(p, 16);
        p += __shfl_xor(p, 8);
        p += __shfl_xor(p, 4);
        p += __shfl_xor(p, 2);
        p += __shfl_xor(p, 1);
        if (lane == 0) outv[n] = p + bb;
    }
}

extern "C" void kernel_launch(void* const* d_in, const int* in_sizes, int n_in,
                              void* d_out, int out_size, void* d_ws, size_t ws_size,
                              hipStream_t stream)
{
    const float* x0   = (const float*)d_in[0];
    const float* ea   = (const float*)d_in[1];
    const float* leW  = (const float*)d_in[2];
    const float* leb  = (const float*)d_in[3];
    const float* W1   = (const float*)d_in[4];
    const float* b1   = (const float*)d_in[5];
    const float* g1   = (const float*)d_in[6];
    const float* bb1  = (const float*)d_in[7];
    const float* W2   = (const float*)d_in[8];
    const float* b2   = (const float*)d_in[9];
    const float* eps  = (const float*)d_in[10];
    const float* og   = (const float*)d_in[11];
    const float* ob   = (const float*)d_in[12];
    const float* cW1  = (const float*)d_in[13];
    const float* cb1  = (const float*)d_in[14];
    const float* cg1  = (const float*)d_in[15];
    const float* cbb1 = (const float*)d_in[16];
    const float* cW2  = (const float*)d_in[17];
    const float* cb2  = (const float*)d_in[18];
    const float* cg2  = (const float*)d_in[19];
    const float* cbb2 = (const float*)d_in[20];
    const float* cW3  = (const float*)d_in[21];
    const float* cb3  = (const float*)d_in[22];
    const int* ei     = (const int*)d_in[23];
    const int* batch  = (const int*)d_in[24];
    const int* src = ei;
    const int* dst = ei + NE;

    // ---- workspace layout (4-byte units). ea_s aliases h128 (disjoint lifetimes).
    float* xbuf   = (float*)d_ws;                      // NN*64
    float* hbuf   = xbuf + (size_t)NN * 64;            // NN*64
    float* eas    = hbuf + (size_t)NN * 64;            // NE*16 (live: layers)
    float* h128   = eas;                               // NN*128 (live: head) — alias
    float* pool   = eas + (size_t)NE * 16;             // NG*64
    float* cstats = pool + (size_t)NG * 64;            // 512
    float* stats  = cstats + 512;                      // 768 (3 x 256)
    int*   cnt    = (int*)(stats + 768);               // NN
    int*   off    = cnt + NN;                          // NN+1 (+pad)
    int*   cur    = off + NN + 4;                      // NN
    int*   bsum   = cur + NN;                          // 256
    int*   boff   = bsum + 256;                        // 256
    int*   srcs   = boff + 256;                        // NE
    int*   dsts   = srcs + NE;                         // NE
    int*   perm   = dsts + NE;                         // NE
    unsigned short* w1h  = (unsigned short*)(perm + NE); // 3*4096 each
    unsigned short* w1l  = w1h + 3 * 4096;
    unsigned short* w2h  = w1l + 3 * 4096;
    unsigned short* w2l  = w2h + 3 * 4096;
    unsigned short* cw1h = w2l + 3 * 4096;               // 16384 each
    unsigned short* cw1l = cw1h + 16384;
    unsigned short* cw2h = cw1l + 16384;
    unsigned short* cw2l = cw2h + 16384;
    float* outp   = (float*)d_out;

    int zeroN = NG * 64 + 512 + 768 + NN;  // pool..cnt contiguous

    int fGrid  = (NN + 63) / 64;         // 782 (MFMA GEMMs)
    int sGrid  = (NE / CH + 3) / 4;      // 6250

    // ---- one-time: zero, weight cvt, CSR build, edge-attr pre-sort
    k_prep<<<512, 256, 0, stream>>>((int*)pool, zeroN);
    k_wcvt<<<8, 256, 0, stream>>>(W1, W2, cW1, cW2, w1h, w1l, w2h, w2l,
                                  cw1h, cw1l, cw2h, cw2l);
    k_hist<<<1024, 256, 0, stream>>>(dst, cnt);
    k_scanA<<<NB_SCAN, 256, 0, stream>>>(cnt, off, bsum);
    k_scanB<<<1, 256, 0, stream>>>(bsum, boff);
    k_scanC<<<NB_SCAN, 256, 0, stream>>>(cnt, off, boff, cur);
    k_scatter<<<1024, 256, 0, stream>>>(src, dst, cur, perm, srcs, dsts);
    k_gather<<<2048, 256, 0, stream>>>(ea, perm, eas);

    for (int l = 0; l < 3; ++l) {
        const float* xc = (l == 0) ? x0 : xbuf;
        float* st = stats + l * 256;
        k_init<<<1024, 256, 0, stream>>>(xc, eps, l, hbuf);
        k_aggr_s<<<sGrid, 256, 0, stream>>>(xc, eas, srcs, dsts,
                leW + l * 1024, leb + l * 64, hbuf);
        k_mm64_f<0, 0><<<fGrid, 256, 0, stream>>>(hbuf, w1h + l * 4096, w1l + l * 4096,
                b1 + l * 64, nullptr, nullptr, nullptr, hbuf, st);
        if (l < 2) {
            k_mm64_f<1, 0><<<fGrid, 256, 0, stream>>>(hbuf, w2h + l * 4096, w2l + l * 4096,
                    b2 + l * 64, st, g1 + l * 64, bb1 + l * 64, hbuf, st + 128);
            k_bn<<<1024, 256, 0, stream>>>(hbuf, st + 128, og + l * 64, ob + l * 64, xbuf);
        } else {
            k_mm64_f<1, 1><<<fGrid, 256, 0, stream>>>(hbuf, w2h + l * 4096, w2l + l * 4096,
                    b2 + l * 64, st, g1 + l * 64, bb1 + l * 64, xbuf, nullptr);
        }
    }
    k_pool<<<1024, 256, 0, stream>>>(xbuf, batch, pool);
    k_cmm_f<0><<<fGrid * 2, 256, 0, stream>>>(xbuf, pool, batch, nullptr, nullptr, nullptr,
                                              cw1h, cw1l, cb1, h128, cstats);
    k_cmm_f<1><<<fGrid * 2, 256, 0, stream>>>(h128, nullptr, nullptr, cstats, cg1, cbb1,
                                              cw2h, cw2l, cb2, h128, cstats + 256);
    k_out<<<1024, 256, 0, stream>>>(h128, cstats + 256, cg2, cbb2, cW3, cb3, outp);
}

// Round 8
// 571.463 us; speedup vs baseline: 2.8244x; 1.4232x over previous
//
#include <hip/hip_runtime.h>

#define NN 50000
#define NE 800000
#define NG 2000
#define BN_EPS 1e-5f
#define NB_SCAN 196   // ceil(NN/256)
#define NCHUNK 50000  // NE/16

typedef __attribute__((ext_vector_type(8))) short bf16x8;
typedef __attribute__((ext_vector_type(4))) float f32x4;

__device__ __forceinline__ float lrelu(float v) { return v > 0.f ? v : 0.01f * v; }

__device__ __forceinline__ unsigned short f2bf(float x) {
    union { float f; unsigned u; } v; v.f = x;
    unsigned r = v.u + 0x7FFF + ((v.u >> 16) & 1);
    return (unsigned short)(r >> 16);
}
__device__ __forceinline__ float bf2f(unsigned short h) {
    union { unsigned u; float f; } v; v.u = ((unsigned)h) << 16;
    return v.f;
}
__device__ __forceinline__ bf16x8 u4_to_bf(uint4 u) {
    union { uint4 q; bf16x8 b; } c; c.q = u; return c.b;
}

// ---- zero pool+cstats+stats+cnt
__global__ __launch_bounds__(256) void k_prep(int* __restrict__ p, int n)
{
    int tid = blockIdx.x * 256 + threadIdx.x;
    for (int i = tid; i < n; i += gridDim.x * 256) p[i] = 0;
}

// ---- convert + transpose GEMM weights to split bf16 (hi+lo) [N][K]
__global__ __launch_bounds__(256) void k_wcvt(
    const float* __restrict__ W1, const float* __restrict__ W2,
    const float* __restrict__ cW1, const float* __restrict__ cW2,
    unsigned short* __restrict__ w1h, unsigned short* __restrict__ w1l,
    unsigned short* __restrict__ w2h, unsigned short* __restrict__ w2l,
    unsigned short* __restrict__ cw1h, unsigned short* __restrict__ cw1l,
    unsigned short* __restrict__ cw2h, unsigned short* __restrict__ cw2l)
{
    int b = blockIdx.x, t = threadIdx.x;
    if (b < 6) {
        const float* s = (b < 3) ? (W1 + b * 4096) : (W2 + (b - 3) * 4096);
        unsigned short* dh = (b < 3) ? (w1h + b * 4096) : (w2h + (b - 3) * 4096);
        unsigned short* dl = (b < 3) ? (w1l + b * 4096) : (w2l + (b - 3) * 4096);
        for (int i = t; i < 4096; i += 256) {
            int k = i >> 6, n = i & 63;
            float v = s[i];
            unsigned short h = f2bf(v);
            dh[n * 64 + k] = h;
            dl[n * 64 + k] = f2bf(v - bf2f(h));
        }
    } else {
        const float* s = (b == 6) ? cW1 : cW2;
        unsigned short* dh = (b == 6) ? cw1h : cw2h;
        unsigned short* dl = (b == 6) ? cw1l : cw2l;
        for (int i = t; i < 16384; i += 256) {
            int k = i >> 7, n = i & 127;
            float v = s[i];
            unsigned short h = f2bf(v);
            dh[n * 128 + k] = h;
            dl[n * 128 + k] = f2bf(v - bf2f(h));
        }
    }
}

// ---- histogram of dst
__global__ __launch_bounds__(256) void k_hist(const int* __restrict__ dst, int* __restrict__ cnt)
{
    int tid = blockIdx.x * 256 + threadIdx.x;
    for (int e = tid; e < NE; e += gridDim.x * 256) atomicAdd(&cnt[dst[e]], 1);
}

__global__ __launch_bounds__(256) void k_scanA(const int* __restrict__ cnt,
    int* __restrict__ off, int* __restrict__ bsum)
{
    __shared__ int s[256];
    int t = threadIdx.x;
    int i = blockIdx.x * 256 + t;
    int v = (i < NN) ? cnt[i] : 0;
    s[t] = v; __syncthreads();
    #pragma unroll
    for (int d = 1; d < 256; d <<= 1) {
        int u = (t >= d) ? s[t - d] : 0;
        __syncthreads();
        s[t] += u;
        __syncthreads();
    }
    if (i < NN) off[i + 1] = s[t];
    if (t == 255) bsum[blockIdx.x] = s[255];
}

__global__ __launch_bounds__(256) void k_scanB(const int* __restrict__ bsum, int* __restrict__ boff)
{
    __shared__ int s[256];
    int t = threadIdx.x;
    int v = (t < NB_SCAN) ? bsum[t] : 0;
    s[t] = v; __syncthreads();
    #pragma unroll
    for (int d = 1; d < 256; d <<= 1) {
        int u = (t >= d) ? s[t - d] : 0;
        __syncthreads();
        s[t] += u;
        __syncthreads();
    }
    boff[t] = s[t] - v;
}

__global__ __launch_bounds__(256) void k_scanC(const int* __restrict__ cnt,
    int* __restrict__ off, const int* __restrict__ boff, int* __restrict__ cur)
{
    int i = blockIdx.x * 256 + threadIdx.x;
    if (i < NN) {
        int incl = off[i + 1] + boff[blockIdx.x];
        off[i + 1] = incl;
        cur[i] = incl - cnt[i];
    }
    if (i == 0) off[0] = 0;
}

// ---- scatter edge ids into dst-sorted order (perm + srcs + dsts)
__global__ __launch_bounds__(256) void k_scatter(const int* __restrict__ src,
    const int* __restrict__ dst, int* __restrict__ cur,
    int* __restrict__ perm, int* __restrict__ srcs, int* __restrict__ dsts)
{
    int tid = blockIdx.x * 256 + threadIdx.x;
    for (int e = tid; e < NE; e += gridDim.x * 256) {
        int d = dst[e];
        int p = atomicAdd(&cur[d], 1);
        perm[p] = e;
        srcs[p] = src[e];
        dsts[p] = d;
    }
}

// ---- gather edge_attr into dst-sorted order, split to bf16 hi/lo
__global__ __launch_bounds__(256) void k_gather(const float* __restrict__ ea,
    const int* __restrict__ perm,
    unsigned short* __restrict__ eash, unsigned short* __restrict__ easl)
{
    int tid = blockIdx.x * 256 + threadIdx.x;
    for (int i = tid; i < NE * 16; i += gridDim.x * 256) {
        int p = i >> 4, j = i & 15;
        float v = ea[(size_t)perm[p] * 16 + j];
        unsigned short h = f2bf(v);
        eash[i] = h;
        easl[i] = f2bf(v - bf2f(h));
    }
}

// ---- aggr = (1+eps[l]) * x
__global__ __launch_bounds__(256) void k_init(const float* __restrict__ x,
    const float* __restrict__ eps, int layer, float* __restrict__ aggr)
{
    int tid = blockIdx.x * 256 + threadIdx.x;
    float s = 1.f + eps[layer];
    const float4* xv = (const float4*)x;
    float4* av = (float4*)aggr;
    for (int i = tid; i < NN * 16; i += gridDim.x * 256) {
        float4 v = xv[i];
        v.x *= s; v.y *= s; v.z *= s; v.w *= s;
        av[i] = v;
    }
}

// ---- MFMA edge aggregation: wave owns 8 chunks x 16 sorted edges.
// e' = ea@We+be via split-bf16 MFMA (K zero-padded to 32); serial phase does
// gather x[src] + add + relu + segment-accumulate with SGPR-uniform dst.
__global__ __launch_bounds__(256) void k_aggr_m(
    const float* __restrict__ x,
    const unsigned short* __restrict__ eash, const unsigned short* __restrict__ easl,
    const int* __restrict__ srcs, const int* __restrict__ dsts,
    const float* __restrict__ We, const float* __restrict__ be,
    float* __restrict__ aggr)
{
    __shared__ unsigned short wth[1024], wtl[1024];  // [col][k] transposed We hi/lo
    __shared__ float els[4 * 16 * 65];               // per-wave e' tile [16 edges][65]
    int t = threadIdx.x;
    // stage We^T (hi/lo) in LDS
    for (int i = t; i < 1024; i += 256) {
        int col = i >> 4, k = i & 15;
        float v = We[k * 64 + col];
        unsigned short h = f2bf(v);
        wth[col * 16 + k] = h;
        wtl[col * 16 + k] = f2bf(v - bf2f(h));
    }
    __syncthreads();

    int lane = t & 63, w = t >> 6;
    float* myels = els + w * (16 * 65);
    int ar = lane & 15;        // A-row / B-col / D-col selector
    int kg = (lane >> 4) & 1;  // k-group for lane<32
    bool klive = lane < 32;

    // hoist B fragments (4 col-chunks x hi/lo) into registers
    bf16x8 bh[4], bl[4];
    float bias4[4];
    #pragma unroll
    for (int nc = 0; nc < 4; ++nc) {
        int col = nc * 16 + ar;
        uint4 hv = {0, 0, 0, 0}, lv = {0, 0, 0, 0};
        if (klive) {
            hv = *(const uint4*)(wth + col * 16 + kg * 8);
            lv = *(const uint4*)(wtl + col * 16 + kg * 8);
        }
        bh[nc] = u4_to_bf(hv);
        bl[nc] = u4_to_bf(lv);
        bias4[nc] = be[col];
    }

    int cbase0 = (blockIdx.x * 4 + w) * 8;  // first chunk of this wave
    for (int ci = 0; ci < 8; ++ci) {
        int chunk = cbase0 + ci;
        if (chunk >= NCHUNK) break;
        int e0 = chunk * 16;

        // load srcs/dsts for the 16 edges (lane-parallel, then readlane)
        int sl = srcs[e0 + ar];
        int dl = dsts[e0 + ar];

        // A fragments (16 edges x K=32 zero-padded), split hi/lo
        uint4 hv = {0, 0, 0, 0}, lv = {0, 0, 0, 0};
        if (klive) {
            size_t ao = (size_t)(e0 + ar) * 16 + kg * 8;
            hv = *(const uint4*)(eash + ao);
            lv = *(const uint4*)(easl + ao);
        }
        bf16x8 ah = u4_to_bf(hv), al = u4_to_bf(lv);

        // issue x gathers early (hide under MFMA)
        float xv[16];
        #pragma unroll
        for (int e = 0; e < 16; ++e) {
            int s_e = __builtin_amdgcn_readlane(sl, e);
            xv[e] = x[(size_t)s_e * 64 + lane];
        }

        // e' = A@We + be for 4 col-chunks; D -> LDS tile
        #pragma unroll
        for (int nc = 0; nc < 4; ++nc) {
            f32x4 acc;
            acc[0] = bias4[nc]; acc[1] = bias4[nc]; acc[2] = bias4[nc]; acc[3] = bias4[nc];
            acc = __builtin_amdgcn_mfma_f32_16x16x32_bf16(ah, bh[nc], acc, 0, 0, 0);
            acc = __builtin_amdgcn_mfma_f32_16x16x32_bf16(al, bh[nc], acc, 0, 0, 0);
            acc = __builtin_amdgcn_mfma_f32_16x16x32_bf16(ah, bl[nc], acc, 0, 0, 0);
            int rbase = (lane >> 4) * 4;
            #pragma unroll
            for (int r = 0; r < 4; ++r)
                myels[(rbase + r) * 65 + nc * 16 + ar] = acc[r];
        }

        // serial segment accumulate (dst is wave-uniform -> scalar branch)
        int d = __builtin_amdgcn_readlane(dl, 0);
        float acc = 0.f;
        #pragma unroll
        for (int e = 0; e < 16; ++e) {
            float m = xv[e] + myels[e * 65 + lane];
            m = fmaxf(m, 0.f);
            acc += m;
            int dn = (e < 15) ? __builtin_amdgcn_readlane(dl, e + 1) : -1;
            if (dn != d) {
                atomicAdd(&aggr[(size_t)d * 64 + lane], acc);
                acc = 0.f;
                d = dn;
            }
        }
    }
}

// ---- split-bf16 MFMA [N,64]@Wt+b: acc = Ah*Wh + Al*Wh + Ah*Wl (fp32-grade).
template<int PRE, int POST>
__global__ __launch_bounds__(256) void k_mm64_f(
    const float* __restrict__ in,
    const unsigned short* __restrict__ Wh, const unsigned short* __restrict__ Wl,
    const float* __restrict__ bias, const float* __restrict__ statsIn,
    const float* __restrict__ gIn, const float* __restrict__ bIn,
    float* __restrict__ out, float* __restrict__ statsOut)
{
    __shared__ unsigned short Ash[64 * 64], Asl[64 * 64];  // [row][k], 16B chunk swizzle cb^(row&7)
    __shared__ unsigned short Bsh[64 * 64], Bsl[64 * 64];  // [n][k], same swizzle
    __shared__ float sc[64], sh[64];
    __shared__ float red[4 * 128];
    int t = threadIdx.x;
    int base = blockIdx.x * 64;
    if (PRE && t < 64) {
        float m = statsIn[t] * (1.f / NN);
        float v = statsIn[64 + t] * (1.f / NN) - m * m;
        float s = gIn[t] * rsqrtf(v + BN_EPS);
        sc[t] = s; sh[t] = bIn[t] - m * s;
    }
    for (int i = t; i < 512; i += 256) {
        int n = i >> 3, cb = i & 7;
        ((uint4*)Bsh)[n * 8 + (cb ^ (n & 7))] = ((const uint4*)Wh)[i];
        ((uint4*)Bsl)[n * 8 + (cb ^ (n & 7))] = ((const uint4*)Wl)[i];
    }
    __syncthreads();
    for (int i = t; i < 512; i += 256) {
        int row = i >> 3, cb = i & 7;
        int node = base + row;
        float v[8] = {0.f, 0.f, 0.f, 0.f, 0.f, 0.f, 0.f, 0.f};
        if (node < NN) {
            float4 u0 = *(const float4*)(in + (size_t)node * 64 + cb * 8);
            float4 u1 = *(const float4*)(in + (size_t)node * 64 + cb * 8 + 4);
            v[0] = u0.x; v[1] = u0.y; v[2] = u0.z; v[3] = u0.w;
            v[4] = u1.x; v[5] = u1.y; v[6] = u1.z; v[7] = u1.w;
            if (PRE) {
                #pragma unroll
                for (int j = 0; j < 8; ++j) {
                    int c = cb * 8 + j;
                    v[j] = lrelu(fmaf(v[j], sc[c], sh[c]));
                }
            }
        }
        unsigned hw[4], lw[4];
        #pragma unroll
        for (int j = 0; j < 4; ++j) {
            unsigned short h0 = f2bf(v[2 * j]), h1 = f2bf(v[2 * j + 1]);
            unsigned short l0 = f2bf(v[2 * j] - bf2f(h0)), l1 = f2bf(v[2 * j + 1] - bf2f(h1));
            hw[j] = (unsigned)h0 | ((unsigned)h1 << 16);
            lw[j] = (unsigned)l0 | ((unsigned)l1 << 16);
        }
        uint4 rh = { hw[0], hw[1], hw[2], hw[3] };
        uint4 rl = { lw[0], lw[1], lw[2], lw[3] };
        int idx = row * 8 + (cb ^ (row & 7));
        ((uint4*)Ash)[idx] = rh;
        ((uint4*)Asl)[idx] = rl;
    }
    __syncthreads();

    int w = t >> 6, l = t & 63;
    int ar = l & 15, kg = l >> 4;
    bf16x8 afh[2], afl[2];
    #pragma unroll
    for (int kt = 0; kt < 2; ++kt) {
        int row = w * 16 + ar, cb = kt * 4 + kg;
        int idx = row * 8 + (cb ^ (row & 7));
        afh[kt] = ((const bf16x8*)Ash)[idx];
        afl[kt] = ((const bf16x8*)Asl)[idx];
    }
    f32x4 acc[4];
    #pragma unroll
    for (int nt = 0; nt < 4; ++nt) { acc[nt][0] = 0.f; acc[nt][1] = 0.f; acc[nt][2] = 0.f; acc[nt][3] = 0.f; }
    #pragma unroll
    for (int nt = 0; nt < 4; ++nt) {
        #pragma unroll
        for (int kt = 0; kt < 2; ++kt) {
            int n = nt * 16 + ar, cb = kt * 4 + kg;
            int idx = n * 8 + (cb ^ (n & 7));
            bf16x8 bfh = ((const bf16x8*)Bsh)[idx];
            bf16x8 bfl = ((const bf16x8*)Bsl)[idx];
            acc[nt] = __builtin_amdgcn_mfma_f32_16x16x32_bf16(afh[kt], bfh, acc[nt], 0, 0, 0);
            acc[nt] = __builtin_amdgcn_mfma_f32_16x16x32_bf16(afl[kt], bfh, acc[nt], 0, 0, 0);
            acc[nt] = __builtin_amdgcn_mfma_f32_16x16x32_bf16(afh[kt], bfl, acc[nt], 0, 0, 0);
        }
    }
    int rb = base + w * 16 + kg * 4;
    #pragma unroll
    for (int nt = 0; nt < 4; ++nt) {
        int col = nt * 16 + ar;
        float bv = bias[col];
        float s = 0.f, q = 0.f;
        #pragma unroll
        for (int r = 0; r < 4; ++r) {
            int node = rb + r;
            float d = acc[nt][r] + bv;
            if (POST == 1) d = lrelu(d);
            if (node < NN) out[(size_t)node * 64 + col] = d;
            if (POST == 0) {
                d = (node < NN) ? d : 0.f;
                s += d; q += d * d;
            }
        }
        if (POST == 0) {
            s += __shfl_xor(s, 16); s += __shfl_xor(s, 32);
            q += __shfl_xor(q, 16); q += __shfl_xor(q, 32);
            if (kg == 0) { red[w * 128 + col] = s; red[w * 128 + 64 + col] = q; }
        }
    }
    if (POST == 0) {
        __syncthreads();
        if (t < 128) {
            int c = t & 63, which = t >> 6;
            float v = red[0 * 128 + which * 64 + c] + red[1 * 128 + which * 64 + c]
                    + red[2 * 128 + which * 64 + c] + red[3 * 128 + which * 64 + c];
            atomicAdd(&statsOut[which * 64 + c], v);
        }
    }
}

// ---- split-bf16 MFMA [N,128]@Wt+b, 64-col blocks (blockIdx.x = row_blk*2 + col_blk).
template<int MODE>
__global__ __launch_bounds__(256) void k_cmm_f(
    const float* __restrict__ inA, const float* __restrict__ pool,
    const int* __restrict__ batch, const float* __restrict__ statsIn,
    const float* __restrict__ gIn, const float* __restrict__ bIn,
    const unsigned short* __restrict__ Wh, const unsigned short* __restrict__ Wl,
    const float* __restrict__ bias,
    float* __restrict__ out, float* __restrict__ statsOut)
{
    __shared__ unsigned short Ash[64 * 128], Asl[64 * 128];  // [row][k] swizzled
    __shared__ unsigned short Bsh[64 * 128], Bsl[64 * 128];  // [nloc][k] swizzled
    __shared__ float sc[128], sh[128];
    __shared__ float red[4 * 128];
    int t = threadIdx.x;
    int base = (blockIdx.x >> 1) * 64;
    int ncol0 = (blockIdx.x & 1) * 64;
    if (MODE == 1 && t < 128) {
        float m = statsIn[t] * (1.f / NN);
        float v = statsIn[128 + t] * (1.f / NN) - m * m;
        float s = gIn[t] * rsqrtf(v + BN_EPS);
        sc[t] = s; sh[t] = bIn[t] - m * s;
    }
    for (int i = t; i < 1024; i += 256) {
        int n = i >> 4, cb = i & 15;
        int idx = n * 16 + (cb ^ (n & 7));
        ((uint4*)Bsh)[idx] = ((const uint4*)Wh)[(ncol0 + n) * 16 + cb];
        ((uint4*)Bsl)[idx] = ((const uint4*)Wl)[(ncol0 + n) * 16 + cb];
    }
    __syncthreads();
    for (int i = t; i < 1024; i += 256) {
        int row = i >> 4, cb = i & 15;
        int node = base + row;
        float v[8] = {0.f, 0.f, 0.f, 0.f, 0.f, 0.f, 0.f, 0.f};
        if (node < NN) {
            const float* sp;
            if (MODE == 0) {
                sp = (cb < 8) ? (inA + (size_t)node * 64 + cb * 8)
                              : (pool + (size_t)batch[node] * 64 + (cb - 8) * 8);
            } else {
                sp = inA + (size_t)node * 128 + cb * 8;
            }
            float4 u0 = *(const float4*)sp;
            float4 u1 = *(const float4*)(sp + 4);
            v[0] = u0.x; v[1] = u0.y; v[2] = u0.z; v[3] = u0.w;
            v[4] = u1.x; v[5] = u1.y; v[6] = u1.z; v[7] = u1.w;
            if (MODE == 1) {
                #pragma unroll
                for (int j = 0; j < 8; ++j) {
                    int c = cb * 8 + j;
                    v[j] = lrelu(fmaf(v[j], sc[c], sh[c]));
                }
            }
        }
        unsigned hw[4], lw[4];
        #pragma unroll
        for (int j = 0; j < 4; ++j) {
            unsigned short h0 = f2bf(v[2 * j]), h1 = f2bf(v[2 * j + 1]);
            unsigned short l0 = f2bf(v[2 * j] - bf2f(h0)), l1 = f2bf(v[2 * j + 1] - bf2f(h1));
            hw[j] = (unsigned)h0 | ((unsigned)h1 << 16);
            lw[j] = (unsigned)l0 | ((unsigned)l1 << 16);
        }
        uint4 rh = { hw[0], hw[1], hw[2], hw[3] };
        uint4 rl = { lw[0], lw[1], lw[2], lw[3] };
        int idx = row * 16 + (cb ^ (row & 7));
        ((uint4*)Ash)[idx] = rh;
        ((uint4*)Asl)[idx] = rl;
    }
    __syncthreads();

    int w = t >> 6, l = t & 63;
    int ar = l & 15, kg = l >> 4;
    bf16x8 afh[4], afl[4];
    #pragma unroll
    for (int kt = 0; kt < 4; ++kt) {
        int row = w * 16 + ar, cb = kt * 4 + kg;
        int idx = row * 16 + (cb ^ (row & 7));
        afh[kt] = ((const bf16x8*)Ash)[idx];
        afl[kt] = ((const bf16x8*)Asl)[idx];
    }
    f32x4 acc[4];
    #pragma unroll
    for (int nt = 0; nt < 4; ++nt) { acc[nt][0] = 0.f; acc[nt][1] = 0.f; acc[nt][2] = 0.f; acc[nt][3] = 0.f; }
    #pragma unroll
    for (int nt = 0; nt < 4; ++nt) {
        #pragma unroll
        for (int kt = 0; kt < 4; ++kt) {
            int n = nt * 16 + ar, cb = kt * 4 + kg;
            int idx = n * 16 + (cb ^ (n & 7));
            bf16x8 bfh = ((const bf16x8*)Bsh)[idx];
            bf16x8 bfl = ((const bf16x8*)Bsl)[idx];
            acc[nt] = __builtin_amdgcn_mfma_f32_16x16x32_bf16(afh[kt], bfh, acc[nt], 0, 0, 0);
            acc[nt] = __builtin_amdgcn_mfma_f32_16x16x32_bf16(afl[kt], bfh, acc[nt], 0, 0, 0);
            acc[nt] = __builtin_amdgcn_mfma_f32_16x16x32_bf16(afh[kt], bfl, acc[nt], 0, 0, 0);
        }
    }
    int rb = base + w * 16 + kg * 4;
    #pragma unroll
    for (int nt = 0; nt < 4; ++nt) {
        int colg = ncol0 + nt * 16 + ar;
        float bv = bias[colg];
        float s = 0.f, q = 0.f;
        #pragma unroll
        for (int r = 0; r < 4; ++r) {
            int node = rb + r;
            float d = acc[nt][r] + bv;
            if (node < NN) out[(size_t)node * 128 + colg] = d;
            d = (node < NN) ? d : 0.f;
            s += d; q += d * d;
        }
        s += __shfl_xor(s, 16); s += __shfl_xor(s, 32);
        q += __shfl_xor(q, 16); q += __shfl_xor(q, 32);
        int col = nt * 16 + ar;
        if (kg == 0) { red[w * 128 + col] = s; red[w * 128 + 64 + col] = q; }
    }
    __syncthreads();
    if (t < 128) {
        int c = t & 63, which = t >> 6;
        float v = red[0 * 128 + which * 64 + c] + red[1 * 128 + which * 64 + c]
                + red[2 * 128 + which * 64 + c] + red[3 * 128 + which * 64 + c];
        atomicAdd(&statsOut[which * 128 + ncol0 + c], v);
    }
}

// ---- elementwise x = lrelu(bn(h)) using stats
__global__ __launch_bounds__(256) void k_bn(
    const float* __restrict__ in, const float* __restrict__ stats,
    const float* __restrict__ g, const float* __restrict__ b,
    float* __restrict__ out)
{
    int tid = blockIdx.x * 256 + threadIdx.x;
    for (int i = tid; i < NN * 16; i += gridDim.x * 256) {
        int c4 = (i & 15) << 2;
        float4 v = ((const float4*)in)[i];
        float o[4] = {v.x, v.y, v.z, v.w};
        #pragma unroll
        for (int j = 0; j < 4; ++j) {
            int c = c4 + j;
            float m = stats[c] * (1.f / NN);
            float vv = stats[64 + c] * (1.f / NN) - m * m;
            float s = g[c] * rsqrtf(vv + BN_EPS);
            o[j] = lrelu(fmaf(o[j] - m, s, b[c]));
        }
        float4 r = {o[0], o[1], o[2], o[3]};
        ((float4*)out)[i] = r;
    }
}

__global__ __launch_bounds__(256) void k_pool(
    const float* __restrict__ x, const int* __restrict__ batch,
    float* __restrict__ pool)
{
    int lane = threadIdx.x & 63;
    int wid = (blockIdx.x * 256 + threadIdx.x) >> 6;
    int nw = (gridDim.x * 256) >> 6;
    for (int n = wid; n < NN; n += nw) {
        int gi = batch[n];
        atomicAdd(&pool[(size_t)gi * 64 + lane], x[(size_t)n * 64 + lane]);
    }
}

// ---- out[n] = lrelu(bn(h128[n])) . cW3 + cb3
__global__ __launch_bounds__(256) void k_out(
    const float* __restrict__ h, const float* __restrict__ stats,
    const float* __restrict__ g, const float* __restrict__ b,
    const float* __restrict__ W3, const float* __restrict__ b3,
    float* __restrict__ outv)
{
    int lane = threadIdx.x & 63;
    int wid = (blockIdx.x * 256 + threadIdx.x) >> 6;
    int nw = (gridDim.x * 256) >> 6;
    float m0 = stats[lane] * (1.f / NN);
    float v0 = stats[128 + lane] * (1.f / NN) - m0 * m0;
    float s0 = g[lane] * rsqrtf(v0 + BN_EPS);
    float h0 = b[lane] - m0 * s0;
    float m1 = stats[64 + lane] * (1.f / NN);
    float v1 = stats[128 + 64 + lane] * (1.f / NN) - m1 * m1;
    float s1 = g[64 + lane] * rsqrtf(v1 + BN_EPS);
    float h1 = b[64 + lane] - m1 * s1;
    float w0 = W3[lane], w1 = W3[64 + lane];
    float bb = b3[0];
    for (int n = wid; n < NN; n += nw) {
        float a = h[(size_t)n * 128 + lane];
        float c = h[(size_t)n * 128 + 64 + lane];
        a = lrelu(fmaf(a, s0, h0));
        c = lrelu(fmaf(c, s1, h1));
        float p = a * w0 + c * w1;
        p += __shfl_xor(p, 32);
        p += __shfl_xor(p, 16);
        p += __shfl_xor(p, 8);
        p += __shfl_xor(p, 4);
        p += __shfl_xor(p, 2);
        p += __shfl_xor(p, 1);
        if (lane == 0) outv[n] = p + bb;
    }
}

extern "C" void kernel_launch(void* const* d_in, const int* in_sizes, int n_in,
                              void* d_out, int out_size, void* d_ws, size_t ws_size,
                              hipStream_t stream)
{
    const float* x0   = (const float*)d_in[0];
    const float* ea   = (const float*)d_in[1];
    const float* leW  = (const float*)d_in[2];
    const float* leb  = (const float*)d_in[3];
    const float* W1   = (const float*)d_in[4];
    const float* b1   = (const float*)d_in[5];
    const float* g1   = (const float*)d_in[6];
    const float* bb1  = (const float*)d_in[7];
    const float* W2   = (const float*)d_in[8];
    const float* b2   = (const float*)d_in[9];
    const float* eps  = (const float*)d_in[10];
    const float* og   = (const float*)d_in[11];
    const float* ob   = (const float*)d_in[12];
    const float* cW1  = (const float*)d_in[13];
    const float* cb1  = (const float*)d_in[14];
    const float* cg1  = (const float*)d_in[15];
    const float* cbb1 = (const float*)d_in[16];
    const float* cW2  = (const float*)d_in[17];
    const float* cb2  = (const float*)d_in[18];
    const float* cg2  = (const float*)d_in[19];
    const float* cbb2 = (const float*)d_in[20];
    const float* cW3  = (const float*)d_in[21];
    const float* cb3  = (const float*)d_in[22];
    const int* ei     = (const int*)d_in[23];
    const int* batch  = (const int*)d_in[24];
    const int* src = ei;
    const int* dst = ei + NE;

    // ---- workspace layout (4-byte units). eash/easl alias h128 (disjoint lifetimes).
    float* xbuf   = (float*)d_ws;                      // NN*64
    float* hbuf   = xbuf + (size_t)NN * 64;            // NN*64
    unsigned short* eash = (unsigned short*)(hbuf + (size_t)NN * 64); // NE*16 ushort
    unsigned short* easl = eash + (size_t)NE * 16;                    // NE*16 ushort
    float* h128   = (float*)eash;                      // NN*128 (live: head) — alias
    float* pool   = (float*)(easl + (size_t)NE * 16);  // NG*64
    float* cstats = pool + (size_t)NG * 64;            // 512
    float* stats  = cstats + 512;                      // 768 (3 x 256)
    int*   cnt    = (int*)(stats + 768);               // NN
    int*   off    = cnt + NN;                          // NN+1 (+pad)
    int*   cur    = off + NN + 4;                      // NN
    int*   bsum   = cur + NN;                          // 256
    int*   boff   = bsum + 256;                        // 256
    int*   srcs   = boff + 256;                        // NE
    int*   dsts   = srcs + NE;                         // NE
    int*   perm   = dsts + NE;                         // NE
    unsigned short* w1h  = (unsigned short*)(perm + NE); // 3*4096 each
    unsigned short* w1l  = w1h + 3 * 4096;
    unsigned short* w2h  = w1l + 3 * 4096;
    unsigned short* w2l  = w2h + 3 * 4096;
    unsigned short* cw1h = w2l + 3 * 4096;               // 16384 each
    unsigned short* cw1l = cw1h + 16384;
    unsigned short* cw2h = cw1l + 16384;
    unsigned short* cw2l = cw2h + 16384;
    float* outp   = (float*)d_out;

    int zeroN = NG * 64 + 512 + 768 + NN;  // pool..cnt contiguous

    int fGrid  = (NN + 63) / 64;            // 782 (MFMA GEMMs)
    int aGrid  = (NCHUNK + 31) / 32;        // 1563 (k_aggr_m: 32 chunks/block)

    // ---- one-time: zero, weight cvt, CSR build, edge-attr pre-sort+split
    k_prep<<<512, 256, 0, stream>>>((int*)pool, zeroN);
    k_wcvt<<<8, 256, 0, stream>>>(W1, W2, cW1, cW2, w1h, w1l, w2h, w2l,
                                  cw1h, cw1l, cw2h, cw2l);
    k_hist<<<1024, 256, 0, stream>>>(dst, cnt);
    k_scanA<<<NB_SCAN, 256, 0, stream>>>(cnt, off, bsum);
    k_scanB<<<1, 256, 0, stream>>>(bsum, boff);
    k_scanC<<<NB_SCAN, 256, 0, stream>>>(cnt, off, boff, cur);
    k_scatter<<<1024, 256, 0, stream>>>(src, dst, cur, perm, srcs, dsts);
    k_gather<<<2048, 256, 0, stream>>>(ea, perm, eash, easl);

    for (int l = 0; l < 3; ++l) {
        const float* xc = (l == 0) ? x0 : xbuf;
        float* st = stats + l * 256;
        k_init<<<1024, 256, 0, stream>>>(xc, eps, l, hbuf);
        k_aggr_m<<<aGrid, 256, 0, stream>>>(xc, eash, easl, srcs, dsts,
                leW + l * 1024, leb + l * 64, hbuf);
        k_mm64_f<0, 0><<<fGrid, 256, 0, stream>>>(hbuf, w1h + l * 4096, w1l + l * 4096,
                b1 + l * 64, nullptr, nullptr, nullptr, hbuf, st);
        if (l < 2) {
            k_mm64_f<1, 0><<<fGrid, 256, 0, stream>>>(hbuf, w2h + l * 4096, w2l + l * 4096,
                    b2 + l * 64, st, g1 + l * 64, bb1 + l * 64, hbuf, st + 128);
            k_bn<<<1024, 256, 0, stream>>>(hbuf, st + 128, og + l * 64, ob + l * 64, xbuf);
        } else {
            k_mm64_f<1, 1><<<fGrid, 256, 0, stream>>>(hbuf, w2h + l * 4096, w2l + l * 4096,
                    b2 + l * 64, st, g1 + l * 64, bb1 + l * 64, xbuf, nullptr);
        }
    }
    k_pool<<<1024, 256, 0, stream>>>(xbuf, batch, pool);
    k_cmm_f<0><<<fGrid * 2, 256, 0, stream>>>(xbuf, pool, batch, nullptr, nullptr, nullptr,
                                              cw1h, cw1l, cb1, h128, cstats);
    k_cmm_f<1><<<fGrid * 2, 256, 0, stream>>>(h128, nullptr, nullptr, cstats, cg1, cbb1,
                                              cw2h, cw2l, cb2, h128, cstats + 256);
    k_out<<<1024, 256, 0, stream>>>(h128, cstats + 256, cg2, cbb2, cW3, cb3, outp);
}

// Round 9
// 553.289 us; speedup vs baseline: 2.9171x; 1.0328x over previous
//
#include <hip/hip_runtime.h>

#define NN 50000
#define NE 800000
#define NG 2000
#define BN_EPS 1e-5f
#define NB_SCAN 196   // ceil(NN/256)
#define NCHUNK 50000  // NE/16

typedef __attribute__((ext_vector_type(8))) short bf16x8;
typedef __attribute__((ext_vector_type(4))) float f32x4;

__device__ __forceinline__ float lrelu(float v) { return v > 0.f ? v : 0.01f * v; }

__device__ __forceinline__ unsigned short f2bf(float x) {
    union { float f; unsigned u; } v; v.f = x;
    unsigned r = v.u + 0x7FFF + ((v.u >> 16) & 1);
    return (unsigned short)(r >> 16);
}
__device__ __forceinline__ float bf2f(unsigned short h) {
    union { unsigned u; float f; } v; v.u = ((unsigned)h) << 16;
    return v.f;
}
__device__ __forceinline__ unsigned pack2hi(float a, float b) {
    return (unsigned)f2bf(a) | ((unsigned)f2bf(b) << 16);
}
__device__ __forceinline__ bf16x8 u4_to_bf(uint4 u) {
    union { uint4 q; bf16x8 b; } c; c.q = u; return c.b;
}

// ---- zero pool+cstats+stats+cnt
__global__ __launch_bounds__(256) void k_prep(int* __restrict__ p, int n)
{
    int tid = blockIdx.x * 256 + threadIdx.x;
    for (int i = tid; i < n; i += gridDim.x * 256) p[i] = 0;
}

// ---- convert + transpose GEMM weights to split bf16 (hi+lo) [N][K]
__global__ __launch_bounds__(256) void k_wcvt(
    const float* __restrict__ W1, const float* __restrict__ W2,
    const float* __restrict__ cW1, const float* __restrict__ cW2,
    unsigned short* __restrict__ w1h, unsigned short* __restrict__ w1l,
    unsigned short* __restrict__ w2h, unsigned short* __restrict__ w2l,
    unsigned short* __restrict__ cw1h, unsigned short* __restrict__ cw1l,
    unsigned short* __restrict__ cw2h, unsigned short* __restrict__ cw2l)
{
    int b = blockIdx.x, t = threadIdx.x;
    if (b < 6) {
        const float* s = (b < 3) ? (W1 + b * 4096) : (W2 + (b - 3) * 4096);
        unsigned short* dh = (b < 3) ? (w1h + b * 4096) : (w2h + (b - 3) * 4096);
        unsigned short* dl = (b < 3) ? (w1l + b * 4096) : (w2l + (b - 3) * 4096);
        for (int i = t; i < 4096; i += 256) {
            int k = i >> 6, n = i & 63;
            float v = s[i];
            unsigned short h = f2bf(v);
            dh[n * 64 + k] = h;
            dl[n * 64 + k] = f2bf(v - bf2f(h));
        }
    } else {
        const float* s = (b == 6) ? cW1 : cW2;
        unsigned short* dh = (b == 6) ? cw1h : cw2h;
        unsigned short* dl = (b == 6) ? cw1l : cw2l;
        for (int i = t; i < 16384; i += 256) {
            int k = i >> 7, n = i & 127;
            float v = s[i];
            unsigned short h = f2bf(v);
            dh[n * 128 + k] = h;
            dl[n * 128 + k] = f2bf(v - bf2f(h));
        }
    }
}

// ---- histogram of dst
__global__ __launch_bounds__(256) void k_hist(const int* __restrict__ dst, int* __restrict__ cnt)
{
    int tid = blockIdx.x * 256 + threadIdx.x;
    for (int e = tid; e < NE; e += gridDim.x * 256) atomicAdd(&cnt[dst[e]], 1);
}

__global__ __launch_bounds__(256) void k_scanA(const int* __restrict__ cnt,
    int* __restrict__ off, int* __restrict__ bsum)
{
    __shared__ int s[256];
    int t = threadIdx.x;
    int i = blockIdx.x * 256 + t;
    int v = (i < NN) ? cnt[i] : 0;
    s[t] = v; __syncthreads();
    #pragma unroll
    for (int d = 1; d < 256; d <<= 1) {
        int u = (t >= d) ? s[t - d] : 0;
        __syncthreads();
        s[t] += u;
        __syncthreads();
    }
    if (i < NN) off[i + 1] = s[t];
    if (t == 255) bsum[blockIdx.x] = s[255];
}

__global__ __launch_bounds__(256) void k_scanB(const int* __restrict__ bsum, int* __restrict__ boff)
{
    __shared__ int s[256];
    int t = threadIdx.x;
    int v = (t < NB_SCAN) ? bsum[t] : 0;
    s[t] = v; __syncthreads();
    #pragma unroll
    for (int d = 1; d < 256; d <<= 1) {
        int u = (t >= d) ? s[t - d] : 0;
        __syncthreads();
        s[t] += u;
        __syncthreads();
    }
    boff[t] = s[t] - v;
}

__global__ __launch_bounds__(256) void k_scanC(const int* __restrict__ cnt,
    int* __restrict__ off, const int* __restrict__ boff, int* __restrict__ cur)
{
    int i = blockIdx.x * 256 + threadIdx.x;
    if (i < NN) {
        int incl = off[i + 1] + boff[blockIdx.x];
        off[i + 1] = incl;
        cur[i] = incl - cnt[i];
    }
    if (i == 0) off[0] = 0;
}

// ---- fused scatter + edge-attr convert: one 64B record per edge (hi16|lo16) + int2 sd
__global__ __launch_bounds__(256) void k_scatter2(
    const int* __restrict__ src, const int* __restrict__ dst,
    int* __restrict__ cur, const float* __restrict__ ea,
    int2* __restrict__ sd, unsigned short* __restrict__ eaz)
{
    int tid = blockIdx.x * 256 + threadIdx.x;
    for (int e = tid; e < NE; e += gridDim.x * 256) {
        int s = src[e], d = dst[e];
        int p = atomicAdd(&cur[d], 1);
        sd[p] = make_int2(s, d);
        const float4* ap = (const float4*)(ea + (size_t)e * 16);
        float4 a0 = ap[0], a1 = ap[1], a2 = ap[2], a3 = ap[3];
        float v[16] = {a0.x, a0.y, a0.z, a0.w, a1.x, a1.y, a1.z, a1.w,
                       a2.x, a2.y, a2.z, a2.w, a3.x, a3.y, a3.z, a3.w};
        unsigned hi[8], lo[8];
        #pragma unroll
        for (int j = 0; j < 8; ++j) {
            unsigned short h0 = f2bf(v[2 * j]), h1 = f2bf(v[2 * j + 1]);
            hi[j] = (unsigned)h0 | ((unsigned)h1 << 16);
            lo[j] = (unsigned)f2bf(v[2 * j] - bf2f(h0))
                  | ((unsigned)f2bf(v[2 * j + 1] - bf2f(h1)) << 16);
        }
        uint4* rec = (uint4*)(eaz + (size_t)p * 32);
        uint4 r0 = {hi[0], hi[1], hi[2], hi[3]};
        uint4 r1 = {hi[4], hi[5], hi[6], hi[7]};
        uint4 r2 = {lo[0], lo[1], lo[2], lo[3]};
        uint4 r3 = {lo[4], lo[5], lo[6], lo[7]};
        rec[0] = r0; rec[1] = r1; rec[2] = r2; rec[3] = r3;
    }
}

// ---- aggr = (1+eps[l]) * x  (only needed for layer 0)
__global__ __launch_bounds__(256) void k_init(const float* __restrict__ x,
    const float* __restrict__ eps, int layer, float* __restrict__ aggr)
{
    int tid = blockIdx.x * 256 + threadIdx.x;
    float s = 1.f + eps[layer];
    const float4* xv = (const float4*)x;
    float4* av = (float4*)aggr;
    for (int i = tid; i < NN * 16; i += gridDim.x * 256) {
        float4 v = xv[i];
        v.x *= s; v.y *= s; v.z *= s; v.w *= s;
        av[i] = v;
    }
}

// ---- MFMA edge aggregation: wave owns 8 chunks x 16 sorted edges.
__global__ __launch_bounds__(256) void k_aggr_m(
    const float* __restrict__ x, const unsigned short* __restrict__ eaz,
    const int2* __restrict__ sd,
    const float* __restrict__ We, const float* __restrict__ be,
    float* __restrict__ aggr)
{
    __shared__ unsigned short wth[1024], wtl[1024];  // [col][k] transposed We hi/lo
    __shared__ float els[4 * 16 * 65];               // per-wave e' tile [16 edges][65]
    int t = threadIdx.x;
    for (int i = t; i < 1024; i += 256) {
        int col = i >> 4, k = i & 15;
        float v = We[k * 64 + col];
        unsigned short h = f2bf(v);
        wth[col * 16 + k] = h;
        wtl[col * 16 + k] = f2bf(v - bf2f(h));
    }
    __syncthreads();

    int lane = t & 63, w = t >> 6;
    float* myels = els + w * (16 * 65);
    int ar = lane & 15;
    int kg = (lane >> 4) & 1;
    bool klive = lane < 32;

    bf16x8 bh[4], bl[4];
    float bias4[4];
    #pragma unroll
    for (int nc = 0; nc < 4; ++nc) {
        int col = nc * 16 + ar;
        uint4 hv = {0, 0, 0, 0}, lv = {0, 0, 0, 0};
        if (klive) {
            hv = *(const uint4*)(wth + col * 16 + kg * 8);
            lv = *(const uint4*)(wtl + col * 16 + kg * 8);
        }
        bh[nc] = u4_to_bf(hv);
        bl[nc] = u4_to_bf(lv);
        bias4[nc] = be[col];
    }

    int cbase0 = (blockIdx.x * 4 + w) * 8;
    for (int ci = 0; ci < 8; ++ci) {
        int chunk = cbase0 + ci;
        if (chunk >= NCHUNK) break;
        int e0 = chunk * 16;

        int2 sdv = sd[e0 + ar];
        int sl = sdv.x, dl = sdv.y;

        uint4 hv = {0, 0, 0, 0}, lv = {0, 0, 0, 0};
        if (klive) {
            const unsigned short* rec = eaz + (size_t)(e0 + ar) * 32;
            hv = *(const uint4*)(rec + kg * 8);
            lv = *(const uint4*)(rec + 16 + kg * 8);
        }
        bf16x8 ah = u4_to_bf(hv), al = u4_to_bf(lv);

        float xv[16];
        #pragma unroll
        for (int e = 0; e < 16; ++e) {
            int s_e = __builtin_amdgcn_readlane(sl, e);
            xv[e] = x[(size_t)s_e * 64 + lane];
        }

        #pragma unroll
        for (int nc = 0; nc < 4; ++nc) {
            f32x4 acc;
            acc[0] = bias4[nc]; acc[1] = bias4[nc]; acc[2] = bias4[nc]; acc[3] = bias4[nc];
            acc = __builtin_amdgcn_mfma_f32_16x16x32_bf16(ah, bh[nc], acc, 0, 0, 0);
            acc = __builtin_amdgcn_mfma_f32_16x16x32_bf16(al, bh[nc], acc, 0, 0, 0);
            acc = __builtin_amdgcn_mfma_f32_16x16x32_bf16(ah, bl[nc], acc, 0, 0, 0);
            int rbase = (lane >> 4) * 4;
            #pragma unroll
            for (int r = 0; r < 4; ++r)
                myels[(rbase + r) * 65 + nc * 16 + ar] = acc[r];
        }

        int d = __builtin_amdgcn_readlane(dl, 0);
        float acc = 0.f;
        #pragma unroll
        for (int e = 0; e < 16; ++e) {
            float m = xv[e] + myels[e * 65 + lane];
            m = fmaxf(m, 0.f);
            acc += m;
            int dn = (e < 15) ? __builtin_amdgcn_readlane(dl, e + 1) : -1;
            if (dn != d) {
                atomicAdd(&aggr[(size_t)d * 64 + lane], acc);
                acc = 0.f;
                d = dn;
            }
        }
    }
}

// ---- split-bf16 MFMA [N,64]@Wt+b. PRE: BN+lrelu input. POST0: raw+stats. POST1: lrelu (+pool).
template<int PRE, int POST>
__global__ __launch_bounds__(256) void k_mm64_f(
    const float* __restrict__ in,
    const unsigned short* __restrict__ Wh, const unsigned short* __restrict__ Wl,
    const float* __restrict__ bias, const float* __restrict__ statsIn,
    const float* __restrict__ gIn, const float* __restrict__ bIn,
    float* __restrict__ out, float* __restrict__ statsOut,
    const int* __restrict__ batch, float* __restrict__ pool)
{
    __shared__ unsigned short Ash[64 * 64], Asl[64 * 64];
    __shared__ unsigned short Bsh[64 * 64], Bsl[64 * 64];
    __shared__ float sc[64], sh[64];
    __shared__ float red[4 * 128];
    int t = threadIdx.x;
    int base = blockIdx.x * 64;
    if (PRE && t < 64) {
        float m = statsIn[t] * (1.f / NN);
        float v = statsIn[64 + t] * (1.f / NN) - m * m;
        float s = gIn[t] * rsqrtf(v + BN_EPS);
        sc[t] = s; sh[t] = bIn[t] - m * s;
    }
    for (int i = t; i < 512; i += 256) {
        int n = i >> 3, cb = i & 7;
        ((uint4*)Bsh)[n * 8 + (cb ^ (n & 7))] = ((const uint4*)Wh)[i];
        ((uint4*)Bsl)[n * 8 + (cb ^ (n & 7))] = ((const uint4*)Wl)[i];
    }
    __syncthreads();
    for (int i = t; i < 512; i += 256) {
        int row = i >> 3, cb = i & 7;
        int node = base + row;
        float v[8] = {0.f, 0.f, 0.f, 0.f, 0.f, 0.f, 0.f, 0.f};
        if (node < NN) {
            float4 u0 = *(const float4*)(in + (size_t)node * 64 + cb * 8);
            float4 u1 = *(const float4*)(in + (size_t)node * 64 + cb * 8 + 4);
            v[0] = u0.x; v[1] = u0.y; v[2] = u0.z; v[3] = u0.w;
            v[4] = u1.x; v[5] = u1.y; v[6] = u1.z; v[7] = u1.w;
            if (PRE) {
                #pragma unroll
                for (int j = 0; j < 8; ++j) {
                    int c = cb * 8 + j;
                    v[j] = lrelu(fmaf(v[j], sc[c], sh[c]));
                }
            }
        }
        unsigned hw[4], lw[4];
        #pragma unroll
        for (int j = 0; j < 4; ++j) {
            unsigned short h0 = f2bf(v[2 * j]), h1 = f2bf(v[2 * j + 1]);
            unsigned short l0 = f2bf(v[2 * j] - bf2f(h0)), l1 = f2bf(v[2 * j + 1] - bf2f(h1));
            hw[j] = (unsigned)h0 | ((unsigned)h1 << 16);
            lw[j] = (unsigned)l0 | ((unsigned)l1 << 16);
        }
        uint4 rh = { hw[0], hw[1], hw[2], hw[3] };
        uint4 rl = { lw[0], lw[1], lw[2], lw[3] };
        int idx = row * 8 + (cb ^ (row & 7));
        ((uint4*)Ash)[idx] = rh;
        ((uint4*)Asl)[idx] = rl;
    }
    __syncthreads();

    int w = t >> 6, l = t & 63;
    int ar = l & 15, kg = l >> 4;
    bf16x8 afh[2], afl[2];
    #pragma unroll
    for (int kt = 0; kt < 2; ++kt) {
        int row = w * 16 + ar, cb = kt * 4 + kg;
        int idx = row * 8 + (cb ^ (row & 7));
        afh[kt] = ((const bf16x8*)Ash)[idx];
        afl[kt] = ((const bf16x8*)Asl)[idx];
    }
    f32x4 acc[4];
    #pragma unroll
    for (int nt = 0; nt < 4; ++nt) { acc[nt][0] = 0.f; acc[nt][1] = 0.f; acc[nt][2] = 0.f; acc[nt][3] = 0.f; }
    #pragma unroll
    for (int nt = 0; nt < 4; ++nt) {
        #pragma unroll
        for (int kt = 0; kt < 2; ++kt) {
            int n = nt * 16 + ar, cb = kt * 4 + kg;
            int idx = n * 8 + (cb ^ (n & 7));
            bf16x8 bfh = ((const bf16x8*)Bsh)[idx];
            bf16x8 bfl = ((const bf16x8*)Bsl)[idx];
            acc[nt] = __builtin_amdgcn_mfma_f32_16x16x32_bf16(afh[kt], bfh, acc[nt], 0, 0, 0);
            acc[nt] = __builtin_amdgcn_mfma_f32_16x16x32_bf16(afl[kt], bfh, acc[nt], 0, 0, 0);
            acc[nt] = __builtin_amdgcn_mfma_f32_16x16x32_bf16(afh[kt], bfl, acc[nt], 0, 0, 0);
        }
    }
    int rb = base + w * 16 + kg * 4;
    int bidx[4];
    if (POST == 1) {
        #pragma unroll
        for (int r = 0; r < 4; ++r)
            bidx[r] = (rb + r < NN) ? batch[rb + r] : 0;
    }
    #pragma unroll
    for (int nt = 0; nt < 4; ++nt) {
        int col = nt * 16 + ar;
        float bv = bias[col];
        float s = 0.f, q = 0.f;
        #pragma unroll
        for (int r = 0; r < 4; ++r) {
            int node = rb + r;
            float d = acc[nt][r] + bv;
            if (POST == 1) d = lrelu(d);
            if (node < NN) {
                out[(size_t)node * 64 + col] = d;
                if (POST == 1)
                    atomicAdd(&pool[(size_t)bidx[r] * 64 + col], d);
            }
            if (POST == 0) {
                d = (node < NN) ? d : 0.f;
                s += d; q += d * d;
            }
        }
        if (POST == 0) {
            s += __shfl_xor(s, 16); s += __shfl_xor(s, 32);
            q += __shfl_xor(q, 16); q += __shfl_xor(q, 32);
            if (kg == 0) { red[w * 128 + col] = s; red[w * 128 + 64 + col] = q; }
        }
    }
    if (POST == 0) {
        __syncthreads();
        if (t < 128) {
            int c = t & 63, which = t >> 6;
            float v = red[0 * 128 + which * 64 + c] + red[1 * 128 + which * 64 + c]
                    + red[2 * 128 + which * 64 + c] + red[3 * 128 + which * 64 + c];
            atomicAdd(&statsOut[which * 64 + c], v);
        }
    }
}

// ---- split-bf16 MFMA [N,128]@Wt+b, 64-col blocks.
template<int MODE>
__global__ __launch_bounds__(256) void k_cmm_f(
    const float* __restrict__ inA, const float* __restrict__ pool,
    const int* __restrict__ batch, const float* __restrict__ statsIn,
    const float* __restrict__ gIn, const float* __restrict__ bIn,
    const unsigned short* __restrict__ Wh, const unsigned short* __restrict__ Wl,
    const float* __restrict__ bias,
    float* __restrict__ out, float* __restrict__ statsOut)
{
    __shared__ unsigned short Ash[64 * 128], Asl[64 * 128];
    __shared__ unsigned short Bsh[64 * 128], Bsl[64 * 128];
    __shared__ float sc[128], sh[128];
    __shared__ float red[4 * 128];
    int t = threadIdx.x;
    int base = (blockIdx.x >> 1) * 64;
    int ncol0 = (blockIdx.x & 1) * 64;
    if (MODE == 1 && t < 128) {
        float m = statsIn[t] * (1.f / NN);
        float v = statsIn[128 + t] * (1.f / NN) - m * m;
        float s = gIn[t] * rsqrtf(v + BN_EPS);
        sc[t] = s; sh[t] = bIn[t] - m * s;
    }
    for (int i = t; i < 1024; i += 256) {
        int n = i >> 4, cb = i & 15;
        int idx = n * 16 + (cb ^ (n & 7));
        ((uint4*)Bsh)[idx] = ((const uint4*)Wh)[(ncol0 + n) * 16 + cb];
        ((uint4*)Bsl)[idx] = ((const uint4*)Wl)[(ncol0 + n) * 16 + cb];
    }
    __syncthreads();
    for (int i = t; i < 1024; i += 256) {
        int row = i >> 4, cb = i & 15;
        int node = base + row;
        float v[8] = {0.f, 0.f, 0.f, 0.f, 0.f, 0.f, 0.f, 0.f};
        if (node < NN) {
            const float* sp;
            if (MODE == 0) {
                sp = (cb < 8) ? (inA + (size_t)node * 64 + cb * 8)
                              : (pool + (size_t)batch[node] * 64 + (cb - 8) * 8);
            } else {
                sp = inA + (size_t)node * 128 + cb * 8;
            }
            float4 u0 = *(const float4*)sp;
            float4 u1 = *(const float4*)(sp + 4);
            v[0] = u0.x; v[1] = u0.y; v[2] = u0.z; v[3] = u0.w;
            v[4] = u1.x; v[5] = u1.y; v[6] = u1.z; v[7] = u1.w;
            if (MODE == 1) {
                #pragma unroll
                for (int j = 0; j < 8; ++j) {
                    int c = cb * 8 + j;
                    v[j] = lrelu(fmaf(v[j], sc[c], sh[c]));
                }
            }
        }
        unsigned hw[4], lw[4];
        #pragma unroll
        for (int j = 0; j < 4; ++j) {
            unsigned short h0 = f2bf(v[2 * j]), h1 = f2bf(v[2 * j + 1]);
            unsigned short l0 = f2bf(v[2 * j] - bf2f(h0)), l1 = f2bf(v[2 * j + 1] - bf2f(h1));
            hw[j] = (unsigned)h0 | ((unsigned)h1 << 16);
            lw[j] = (unsigned)l0 | ((unsigned)l1 << 16);
        }
        uint4 rh = { hw[0], hw[1], hw[2], hw[3] };
        uint4 rl = { lw[0], lw[1], lw[2], lw[3] };
        int idx = row * 16 + (cb ^ (row & 7));
        ((uint4*)Ash)[idx] = rh;
        ((uint4*)Asl)[idx] = rl;
    }
    __syncthreads();

    int w = t >> 6, l = t & 63;
    int ar = l & 15, kg = l >> 4;
    bf16x8 afh[4], afl[4];
    #pragma unroll
    for (int kt = 0; kt < 4; ++kt) {
        int row = w * 16 + ar, cb = kt * 4 + kg;
        int idx = row * 16 + (cb ^ (row & 7));
        afh[kt] = ((const bf16x8*)Ash)[idx];
        afl[kt] = ((const bf16x8*)Asl)[idx];
    }
    f32x4 acc[4];
    #pragma unroll
    for (int nt = 0; nt < 4; ++nt) { acc[nt][0] = 0.f; acc[nt][1] = 0.f; acc[nt][2] = 0.f; acc[nt][3] = 0.f; }
    #pragma unroll
    for (int nt = 0; nt < 4; ++nt) {
        #pragma unroll
        for (int kt = 0; kt < 4; ++kt) {
            int n = nt * 16 + ar, cb = kt * 4 + kg;
            int idx = n * 16 + (cb ^ (n & 7));
            bf16x8 bfh = ((const bf16x8*)Bsh)[idx];
            bf16x8 bfl = ((const bf16x8*)Bsl)[idx];
            acc[nt] = __builtin_amdgcn_mfma_f32_16x16x32_bf16(afh[kt], bfh, acc[nt], 0, 0, 0);
            acc[nt] = __builtin_amdgcn_mfma_f32_16x16x32_bf16(afl[kt], bfh, acc[nt], 0, 0, 0);
            acc[nt] = __builtin_amdgcn_mfma_f32_16x16x32_bf16(afh[kt], bfl, acc[nt], 0, 0, 0);
        }
    }
    int rb = base + w * 16 + kg * 4;
    #pragma unroll
    for (int nt = 0; nt < 4; ++nt) {
        int colg = ncol0 + nt * 16 + ar;
        float bv = bias[colg];
        float s = 0.f, q = 0.f;
        #pragma unroll
        for (int r = 0; r < 4; ++r) {
            int node = rb + r;
            float d = acc[nt][r] + bv;
            if (node < NN) out[(size_t)node * 128 + colg] = d;
            d = (node < NN) ? d : 0.f;
            s += d; q += d * d;
        }
        s += __shfl_xor(s, 16); s += __shfl_xor(s, 32);
        q += __shfl_xor(q, 16); q += __shfl_xor(q, 32);
        int col = nt * 16 + ar;
        if (kg == 0) { red[w * 128 + col] = s; red[w * 128 + 64 + col] = q; }
    }
    __syncthreads();
    if (t < 128) {
        int c = t & 63, which = t >> 6;
        float v = red[0 * 128 + which * 64 + c] + red[1 * 128 + which * 64 + c]
                + red[2 * 128 + which * 64 + c] + red[3 * 128 + which * 64 + c];
        atomicAdd(&statsOut[which * 128 + ncol0 + c], v);
    }
}

// ---- fused: x = lrelu(bn(h)); aggrOut = (1+eps[nextLayer]) * x
__global__ __launch_bounds__(256) void k_bn2(
    const float* __restrict__ in, const float* __restrict__ stats,
    const float* __restrict__ g, const float* __restrict__ b,
    const float* __restrict__ eps, int nextLayer,
    float* __restrict__ xout, float* __restrict__ aggrOut)
{
    int tid = blockIdx.x * 256 + threadIdx.x;
    float e1 = 1.f + eps[nextLayer];
    for (int i = tid; i < NN * 16; i += gridDim.x * 256) {
        int c4 = (i & 15) << 2;
        float4 v = ((const float4*)in)[i];
        float o[4] = {v.x, v.y, v.z, v.w};
        #pragma unroll
        for (int j = 0; j < 4; ++j) {
            int c = c4 + j;
            float m = stats[c] * (1.f / NN);
            float vv = stats[64 + c] * (1.f / NN) - m * m;
            float s = g[c] * rsqrtf(vv + BN_EPS);
            o[j] = lrelu(fmaf(o[j] - m, s, b[c]));
        }
        float4 r = {o[0], o[1], o[2], o[3]};
        ((float4*)xout)[i] = r;
        float4 r2 = {o[0] * e1, o[1] * e1, o[2] * e1, o[3] * e1};
        ((float4*)aggrOut)[i] = r2;
    }
}

// ---- out[n] = lrelu(bn(h128[n])) . cW3 + cb3
__global__ __launch_bounds__(256) void k_out(
    const float* __restrict__ h, const float* __restrict__ stats,
    const float* __restrict__ g, const float* __restrict__ b,
    const float* __restrict__ W3, const float* __restrict__ b3,
    float* __restrict__ outv)
{
    int lane = threadIdx.x & 63;
    int wid = (blockIdx.x * 256 + threadIdx.x) >> 6;
    int nw = (gridDim.x * 256) >> 6;
    float m0 = stats[lane] * (1.f / NN);
    float v0 = stats[128 + lane] * (1.f / NN) - m0 * m0;
    float s0 = g[lane] * rsqrtf(v0 + BN_EPS);
    float h0 = b[lane] - m0 * s0;
    float m1 = stats[64 + lane] * (1.f / NN);
    float v1 = stats[128 + 64 + lane] * (1.f / NN) - m1 * m1;
    float s1 = g[64 + lane] * rsqrtf(v1 + BN_EPS);
    float h1 = b[64 + lane] - m1 * s1;
    float w0 = W3[lane], w1 = W3[64 + lane];
    float bb = b3[0];
    for (int n = wid; n < NN; n += nw) {
        float a = h[(size_t)n * 128 + lane];
        float c = h[(size_t)n * 128 + 64 + lane];
        a = lrelu(fmaf(a, s0, h0));
        c = lrelu(fmaf(c, s1, h1));
        float p = a * w0 + c * w1;
        p += __shfl_xor(p, 32);
        p += __shfl_xor(p, 16);
        p += __shfl_xor(p, 8);
        p += __shfl_xor(p, 4);
        p += __shfl_xor(p, 2);
        p += __shfl_xor(p, 1);
        if (lane == 0) outv[n] = p + bb;
    }
}

extern "C" void kernel_launch(void* const* d_in, const int* in_sizes, int n_in,
                              void* d_out, int out_size, void* d_ws, size_t ws_size,
                              hipStream_t stream)
{
    const float* x0   = (const float*)d_in[0];
    const float* ea   = (const float*)d_in[1];
    const float* leW  = (const float*)d_in[2];
    const float* leb  = (const float*)d_in[3];
    const float* W1   = (const float*)d_in[4];
    const float* b1   = (const float*)d_in[5];
    const float* g1   = (const float*)d_in[6];
    const float* bb1  = (const float*)d_in[7];
    const float* W2   = (const float*)d_in[8];
    const float* b2   = (const float*)d_in[9];
    const float* eps  = (const float*)d_in[10];
    const float* og   = (const float*)d_in[11];
    const float* ob   = (const float*)d_in[12];
    const float* cW1  = (const float*)d_in[13];
    const float* cb1  = (const float*)d_in[14];
    const float* cg1  = (const float*)d_in[15];
    const float* cbb1 = (const float*)d_in[16];
    const float* cW2  = (const float*)d_in[17];
    const float* cb2  = (const float*)d_in[18];
    const float* cg2  = (const float*)d_in[19];
    const float* cbb2 = (const float*)d_in[20];
    const float* cW3  = (const float*)d_in[21];
    const float* cb3  = (const float*)d_in[22];
    const int* ei     = (const int*)d_in[23];
    const int* batch  = (const int*)d_in[24];
    const int* src = ei;
    const int* dst = ei + NE;

    // ---- workspace layout (4-byte units). eaz aliases h128 (disjoint lifetimes).
    float* xbuf   = (float*)d_ws;                       // NN*64
    float* hbuf   = xbuf + (size_t)NN * 64;             // NN*64
    unsigned short* eaz = (unsigned short*)(hbuf + (size_t)NN * 64); // NE*32 ushort (64B/edge)
    float* h128   = (float*)eaz;                        // NN*128 (head) — alias
    float* pool   = (float*)(eaz + (size_t)NE * 32);    // NG*64
    float* cstats = pool + (size_t)NG * 64;             // 512
    float* stats  = cstats + 512;                       // 768 (3 x 256)
    int*   cnt    = (int*)(stats + 768);                // NN
    int*   off    = cnt + NN;                           // NN+1 (+pad)
    int*   cur    = off + NN + 4;                       // NN
    int*   bsum   = cur + NN;                           // 256
    int*   boff   = bsum + 256;                         // 256
    int2*  sd     = (int2*)(boff + 256);                // NE int2
    unsigned short* w1h  = (unsigned short*)(sd + NE);  // 3*4096 each
    unsigned short* w1l  = w1h + 3 * 4096;
    unsigned short* w2h  = w1l + 3 * 4096;
    unsigned short* w2l  = w2h + 3 * 4096;
    unsigned short* cw1h = w2l + 3 * 4096;              // 16384 each
    unsigned short* cw1l = cw1h + 16384;
    unsigned short* cw2h = cw1l + 16384;
    unsigned short* cw2l = cw2h + 16384;
    float* outp   = (float*)d_out;

    int zeroN = NG * 64 + 512 + 768 + NN;  // pool..cnt contiguous

    int fGrid  = (NN + 63) / 64;            // 782 (MFMA GEMMs)
    int aGrid  = (NCHUNK + 31) / 32;        // 1563 (k_aggr_m: 32 chunks/block)

    // ---- one-time: zero, weight cvt, CSR build, fused scatter+convert
    k_prep<<<512, 256, 0, stream>>>((int*)pool, zeroN);
    k_wcvt<<<8, 256, 0, stream>>>(W1, W2, cW1, cW2, w1h, w1l, w2h, w2l,
                                  cw1h, cw1l, cw2h, cw2l);
    k_hist<<<1024, 256, 0, stream>>>(dst, cnt);
    k_scanA<<<NB_SCAN, 256, 0, stream>>>(cnt, off, bsum);
    k_scanB<<<1, 256, 0, stream>>>(bsum, boff);
    k_scanC<<<NB_SCAN, 256, 0, stream>>>(cnt, off, boff, cur);
    k_scatter2<<<2048, 256, 0, stream>>>(src, dst, cur, ea, sd, eaz);

    k_init<<<1024, 256, 0, stream>>>(x0, eps, 0, hbuf);
    for (int l = 0; l < 3; ++l) {
        const float* xc = (l == 0) ? x0 : xbuf;
        float* st = stats + l * 256;
        k_aggr_m<<<aGrid, 256, 0, stream>>>(xc, eaz, sd,
                leW + l * 1024, leb + l * 64, hbuf);
        k_mm64_f<0, 0><<<fGrid, 256, 0, stream>>>(hbuf, w1h + l * 4096, w1l + l * 4096,
                b1 + l * 64, nullptr, nullptr, nullptr, hbuf, st, nullptr, nullptr);
        if (l < 2) {
            k_mm64_f<1, 0><<<fGrid, 256, 0, stream>>>(hbuf, w2h + l * 4096, w2l + l * 4096,
                    b2 + l * 64, st, g1 + l * 64, bb1 + l * 64, hbuf, st + 128,
                    nullptr, nullptr);
            k_bn2<<<1024, 256, 0, stream>>>(hbuf, st + 128, og + l * 64, ob + l * 64,
                    eps, l + 1, xbuf, hbuf);
        } else {
            k_mm64_f<1, 1><<<fGrid, 256, 0, stream>>>(hbuf, w2h + l * 4096, w2l + l * 4096,
                    b2 + l * 64, st, g1 + l * 64, bb1 + l * 64, xbuf, nullptr,
                    batch, pool);
        }
    }
    k_cmm_f<0><<<fGrid * 2, 256, 0, stream>>>(xbuf, pool, batch, nullptr, nullptr, nullptr,
                                              cw1h, cw1l, cb1, h128, cstats);
    k_cmm_f<1><<<fGrid * 2, 256, 0, stream>>>(h128, nullptr, nullptr, cstats, cg1, cbb1,
                                              cw2h, cw2l, cb2, h128, cstats + 256);
    k_out<<<1024, 256, 0, stream>>>(h128, cstats + 256, cg2, cbb2, cW3, cb3, outp);
}

// Round 10
// 544.202 us; speedup vs baseline: 2.9658x; 1.0167x over previous
//
#include <hip/hip_runtime.h>

#define NN 50000
#define NE 800000
#define NG 2000
#define BN_EPS 1e-5f
#define NB_SCAN 196   // ceil(NN/256)
#define NCHUNK 50000  // NE/16

typedef __attribute__((ext_vector_type(8))) short bf16x8;
typedef __attribute__((ext_vector_type(4))) float f32x4;

__device__ __forceinline__ float lrelu(float v) { return v > 0.f ? v : 0.01f * v; }

__device__ __forceinline__ unsigned short f2bf(float x) {
    union { float f; unsigned u; } v; v.f = x;
    unsigned r = v.u + 0x7FFF + ((v.u >> 16) & 1);
    return (unsigned short)(r >> 16);
}
__device__ __forceinline__ float bf2f(unsigned short h) {
    union { unsigned u; float f; } v; v.u = ((unsigned)h) << 16;
    return v.f;
}
__device__ __forceinline__ bf16x8 u4_to_bf(uint4 u) {
    union { uint4 q; bf16x8 b; } c; c.q = u; return c.b;
}

// ---- zero pool+cstats+stats+cnt
__global__ __launch_bounds__(256) void k_prep(int* __restrict__ p, int n)
{
    int tid = blockIdx.x * 256 + threadIdx.x;
    for (int i = tid; i < n; i += gridDim.x * 256) p[i] = 0;
}

// ---- convert + transpose GEMM weights to split bf16 (hi+lo) [N][K]
__global__ __launch_bounds__(256) void k_wcvt(
    const float* __restrict__ W1, const float* __restrict__ W2,
    const float* __restrict__ cW1, const float* __restrict__ cW2,
    unsigned short* __restrict__ w1h, unsigned short* __restrict__ w1l,
    unsigned short* __restrict__ w2h, unsigned short* __restrict__ w2l,
    unsigned short* __restrict__ cw1h, unsigned short* __restrict__ cw1l,
    unsigned short* __restrict__ cw2h, unsigned short* __restrict__ cw2l)
{
    int b = blockIdx.x, t = threadIdx.x;
    if (b < 6) {
        const float* s = (b < 3) ? (W1 + b * 4096) : (W2 + (b - 3) * 4096);
        unsigned short* dh = (b < 3) ? (w1h + b * 4096) : (w2h + (b - 3) * 4096);
        unsigned short* dl = (b < 3) ? (w1l + b * 4096) : (w2l + (b - 3) * 4096);
        for (int i = t; i < 4096; i += 256) {
            int k = i >> 6, n = i & 63;
            float v = s[i];
            unsigned short h = f2bf(v);
            dh[n * 64 + k] = h;
            dl[n * 64 + k] = f2bf(v - bf2f(h));
        }
    } else {
        const float* s = (b == 6) ? cW1 : cW2;
        unsigned short* dh = (b == 6) ? cw1h : cw2h;
        unsigned short* dl = (b == 6) ? cw1l : cw2l;
        for (int i = t; i < 16384; i += 256) {
            int k = i >> 7, n = i & 127;
            float v = s[i];
            unsigned short h = f2bf(v);
            dh[n * 128 + k] = h;
            dl[n * 128 + k] = f2bf(v - bf2f(h));
        }
    }
}

// ---- histogram of dst
__global__ __launch_bounds__(256) void k_hist(const int* __restrict__ dst, int* __restrict__ cnt)
{
    int tid = blockIdx.x * 256 + threadIdx.x;
    for (int e = tid; e < NE; e += gridDim.x * 256) atomicAdd(&cnt[dst[e]], 1);
}

__global__ __launch_bounds__(256) void k_scanA(const int* __restrict__ cnt,
    int* __restrict__ off, int* __restrict__ bsum)
{
    __shared__ int s[256];
    int t = threadIdx.x;
    int i = blockIdx.x * 256 + t;
    int v = (i < NN) ? cnt[i] : 0;
    s[t] = v; __syncthreads();
    #pragma unroll
    for (int d = 1; d < 256; d <<= 1) {
        int u = (t >= d) ? s[t - d] : 0;
        __syncthreads();
        s[t] += u;
        __syncthreads();
    }
    if (i < NN) off[i + 1] = s[t];
    if (t == 255) bsum[blockIdx.x] = s[255];
}

__global__ __launch_bounds__(256) void k_scanB(const int* __restrict__ bsum, int* __restrict__ boff)
{
    __shared__ int s[256];
    int t = threadIdx.x;
    int v = (t < NB_SCAN) ? bsum[t] : 0;
    s[t] = v; __syncthreads();
    #pragma unroll
    for (int d = 1; d < 256; d <<= 1) {
        int u = (t >= d) ? s[t - d] : 0;
        __syncthreads();
        s[t] += u;
        __syncthreads();
    }
    boff[t] = s[t] - v;
}

__global__ __launch_bounds__(256) void k_scanC(const int* __restrict__ cnt,
    int* __restrict__ off, const int* __restrict__ boff, int* __restrict__ cur)
{
    int i = blockIdx.x * 256 + threadIdx.x;
    if (i < NN) {
        int incl = off[i + 1] + boff[blockIdx.x];
        off[i + 1] = incl;
        cur[i] = incl - cnt[i];
    }
    if (i == 0) off[0] = 0;
}

// ---- fused scatter + edge-attr convert: ONE 64B record per edge:
// [16 bf16 hi | 12 bf16 lo | src int | dst int]  (lo for k=12..15 dropped)
__global__ __launch_bounds__(256) void k_scatter2(
    const int* __restrict__ src, const int* __restrict__ dst,
    int* __restrict__ cur, const float* __restrict__ ea,
    unsigned short* __restrict__ eaz)
{
    int tid = blockIdx.x * 256 + threadIdx.x;
    for (int e = tid; e < NE; e += gridDim.x * 256) {
        int s = src[e], d = dst[e];
        int p = atomicAdd(&cur[d], 1);
        const float4* ap = (const float4*)(ea + (size_t)e * 16);
        float4 a0 = ap[0], a1 = ap[1], a2 = ap[2], a3 = ap[3];
        float v[16] = {a0.x, a0.y, a0.z, a0.w, a1.x, a1.y, a1.z, a1.w,
                       a2.x, a2.y, a2.z, a2.w, a3.x, a3.y, a3.z, a3.w};
        unsigned hi[8], lo[6];
        #pragma unroll
        for (int j = 0; j < 8; ++j) {
            unsigned short h0 = f2bf(v[2 * j]), h1 = f2bf(v[2 * j + 1]);
            hi[j] = (unsigned)h0 | ((unsigned)h1 << 16);
            if (j < 6)
                lo[j] = (unsigned)f2bf(v[2 * j] - bf2f(f2bf(v[2 * j])))
                      | ((unsigned)f2bf(v[2 * j + 1] - bf2f(f2bf(v[2 * j + 1]))) << 16);
        }
        uint4* rec = (uint4*)(eaz + (size_t)p * 32);
        uint4 r0 = {hi[0], hi[1], hi[2], hi[3]};
        uint4 r1 = {hi[4], hi[5], hi[6], hi[7]};
        uint4 r2 = {lo[0], lo[1], lo[2], lo[3]};
        uint4 r3 = {lo[4], lo[5], (unsigned)s, (unsigned)d};
        rec[0] = r0; rec[1] = r1; rec[2] = r2; rec[3] = r3;
    }
}

// ---- aggr = (1+eps[l]) * x  (layer 0 only; later layers fused into k_bn2)
__global__ __launch_bounds__(256) void k_init(const float* __restrict__ x,
    const float* __restrict__ eps, int layer, float* __restrict__ aggr)
{
    int tid = blockIdx.x * 256 + threadIdx.x;
    float s = 1.f + eps[layer];
    const float4* xv = (const float4*)x;
    float4* av = (float4*)aggr;
    for (int i = tid; i < NN * 16; i += gridDim.x * 256) {
        float4 v = xv[i];
        v.x *= s; v.y *= s; v.z *= s; v.w *= s;
        av[i] = v;
    }
}

// ---- MFMA edge aggregation: wave owns 8 chunks x 16 sorted edges.
__global__ __launch_bounds__(256) void k_aggr_m(
    const float* __restrict__ x, const unsigned short* __restrict__ eaz,
    const float* __restrict__ We, const float* __restrict__ be,
    float* __restrict__ aggr)
{
    __shared__ unsigned short wth[1024], wtl[1024];  // [col][k] transposed We hi/lo
    __shared__ float els[4 * 16 * 65];               // per-wave e' tile [16 edges][65]
    int t = threadIdx.x;
    for (int i = t; i < 1024; i += 256) {
        int col = i >> 4, k = i & 15;
        float v = We[k * 64 + col];
        unsigned short h = f2bf(v);
        wth[col * 16 + k] = h;
        wtl[col * 16 + k] = f2bf(v - bf2f(h));
    }
    __syncthreads();

    int lane = t & 63, w = t >> 6;
    float* myels = els + w * (16 * 65);
    int ar = lane & 15;
    int kg = (lane >> 4) & 1;
    bool klive = lane < 32;

    bf16x8 bh[4], bl[4];
    float bias4[4];
    #pragma unroll
    for (int nc = 0; nc < 4; ++nc) {
        int col = nc * 16 + ar;
        uint4 hv = {0, 0, 0, 0}, lv = {0, 0, 0, 0};
        if (klive) {
            hv = *(const uint4*)(wth + col * 16 + kg * 8);
            lv = *(const uint4*)(wtl + col * 16 + kg * 8);
        }
        bh[nc] = u4_to_bf(hv);
        bl[nc] = u4_to_bf(lv);
        bias4[nc] = be[col];
    }

    int cbase0 = (blockIdx.x * 4 + w) * 8;
    for (int ci = 0; ci < 8; ++ci) {
        int chunk = cbase0 + ci;
        if (chunk >= NCHUNK) break;
        int e0 = chunk * 16;
        const unsigned short* rec = eaz + (size_t)(e0 + ar) * 32;

        // src/dst live in the record tail (same 64B line as fragments)
        int2 sdv = *(const int2*)(rec + 28);
        int sl = sdv.x, dl = sdv.y;

        uint4 hv = {0, 0, 0, 0}, lv = {0, 0, 0, 0};
        if (klive) {
            hv = *(const uint4*)(rec + kg * 8);
            lv = *(const uint4*)(rec + 16 + kg * 8);
            if (kg) { lv.z = 0; lv.w = 0; }  // tail words hold src/dst, not lo
        }
        bf16x8 ah = u4_to_bf(hv), al = u4_to_bf(lv);

        float xv[16];
        #pragma unroll
        for (int e = 0; e < 16; ++e) {
            int s_e = __builtin_amdgcn_readlane(sl, e);
            xv[e] = x[(size_t)s_e * 64 + lane];
        }

        #pragma unroll
        for (int nc = 0; nc < 4; ++nc) {
            f32x4 acc;
            acc[0] = bias4[nc]; acc[1] = bias4[nc]; acc[2] = bias4[nc]; acc[3] = bias4[nc];
            acc = __builtin_amdgcn_mfma_f32_16x16x32_bf16(ah, bh[nc], acc, 0, 0, 0);
            acc = __builtin_amdgcn_mfma_f32_16x16x32_bf16(al, bh[nc], acc, 0, 0, 0);
            acc = __builtin_amdgcn_mfma_f32_16x16x32_bf16(ah, bl[nc], acc, 0, 0, 0);
            int rbase = (lane >> 4) * 4;
            #pragma unroll
            for (int r = 0; r < 4; ++r)
                myels[(rbase + r) * 65 + nc * 16 + ar] = acc[r];
        }

        int d = __builtin_amdgcn_readlane(dl, 0);
        float acc = 0.f;
        #pragma unroll
        for (int e = 0; e < 16; ++e) {
            float m = xv[e] + myels[e * 65 + lane];
            m = fmaxf(m, 0.f);
            acc += m;
            int dn = (e < 15) ? __builtin_amdgcn_readlane(dl, e + 1) : -1;
            if (dn != d) {
                atomicAdd(&aggr[(size_t)d * 64 + lane], acc);
                acc = 0.f;
                d = dn;
            }
        }
    }
}

// ---- split-bf16 MFMA [N,64]@Wt+b. PRE: BN+lrelu input. POST0: raw+stats. POST1: lrelu (+pool).
template<int PRE, int POST>
__global__ __launch_bounds__(256) void k_mm64_f(
    const float* __restrict__ in,
    const unsigned short* __restrict__ Wh, const unsigned short* __restrict__ Wl,
    const float* __restrict__ bias, const float* __restrict__ statsIn,
    const float* __restrict__ gIn, const float* __restrict__ bIn,
    float* __restrict__ out, float* __restrict__ statsOut,
    const int* __restrict__ batch, float* __restrict__ pool)
{
    __shared__ unsigned short Ash[64 * 64], Asl[64 * 64];
    __shared__ unsigned short Bsh[64 * 64], Bsl[64 * 64];
    __shared__ float sc[64], sh[64];
    __shared__ float red[4 * 128];
    int t = threadIdx.x;
    int base = blockIdx.x * 64;
    if (PRE && t < 64) {
        float m = statsIn[t] * (1.f / NN);
        float v = statsIn[64 + t] * (1.f / NN) - m * m;
        float s = gIn[t] * rsqrtf(v + BN_EPS);
        sc[t] = s; sh[t] = bIn[t] - m * s;
    }
    for (int i = t; i < 512; i += 256) {
        int n = i >> 3, cb = i & 7;
        ((uint4*)Bsh)[n * 8 + (cb ^ (n & 7))] = ((const uint4*)Wh)[i];
        ((uint4*)Bsl)[n * 8 + (cb ^ (n & 7))] = ((const uint4*)Wl)[i];
    }
    __syncthreads();
    for (int i = t; i < 512; i += 256) {
        int row = i >> 3, cb = i & 7;
        int node = base + row;
        float v[8] = {0.f, 0.f, 0.f, 0.f, 0.f, 0.f, 0.f, 0.f};
        if (node < NN) {
            float4 u0 = *(const float4*)(in + (size_t)node * 64 + cb * 8);
            float4 u1 = *(const float4*)(in + (size_t)node * 64 + cb * 8 + 4);
            v[0] = u0.x; v[1] = u0.y; v[2] = u0.z; v[3] = u0.w;
            v[4] = u1.x; v[5] = u1.y; v[6] = u1.z; v[7] = u1.w;
            if (PRE) {
                #pragma unroll
                for (int j = 0; j < 8; ++j) {
                    int c = cb * 8 + j;
                    v[j] = lrelu(fmaf(v[j], sc[c], sh[c]));
                }
            }
        }
        unsigned hw[4], lw[4];
        #pragma unroll
        for (int j = 0; j < 4; ++j) {
            unsigned short h0 = f2bf(v[2 * j]), h1 = f2bf(v[2 * j + 1]);
            unsigned short l0 = f2bf(v[2 * j] - bf2f(h0)), l1 = f2bf(v[2 * j + 1] - bf2f(h1));
            hw[j] = (unsigned)h0 | ((unsigned)h1 << 16);
            lw[j] = (unsigned)l0 | ((unsigned)l1 << 16);
        }
        uint4 rh = { hw[0], hw[1], hw[2], hw[3] };
        uint4 rl = { lw[0], lw[1], lw[2], lw[3] };
        int idx = row * 8 + (cb ^ (row & 7));
        ((uint4*)Ash)[idx] = rh;
        ((uint4*)Asl)[idx] = rl;
    }
    __syncthreads();

    int w = t >> 6, l = t & 63;
    int ar = l & 15, kg = l >> 4;
    bf16x8 afh[2], afl[2];
    #pragma unroll
    for (int kt = 0; kt < 2; ++kt) {
        int row = w * 16 + ar, cb = kt * 4 + kg;
        int idx = row * 8 + (cb ^ (row & 7));
        afh[kt] = ((const bf16x8*)Ash)[idx];
        afl[kt] = ((const bf16x8*)Asl)[idx];
    }
    f32x4 acc[4];
    #pragma unroll
    for (int nt = 0; nt < 4; ++nt) { acc[nt][0] = 0.f; acc[nt][1] = 0.f; acc[nt][2] = 0.f; acc[nt][3] = 0.f; }
    #pragma unroll
    for (int nt = 0; nt < 4; ++nt) {
        #pragma unroll
        for (int kt = 0; kt < 2; ++kt) {
            int n = nt * 16 + ar, cb = kt * 4 + kg;
            int idx = n * 8 + (cb ^ (n & 7));
            bf16x8 bfh = ((const bf16x8*)Bsh)[idx];
            bf16x8 bfl = ((const bf16x8*)Bsl)[idx];
            acc[nt] = __builtin_amdgcn_mfma_f32_16x16x32_bf16(afh[kt], bfh, acc[nt], 0, 0, 0);
            acc[nt] = __builtin_amdgcn_mfma_f32_16x16x32_bf16(afl[kt], bfh, acc[nt], 0, 0, 0);
            acc[nt] = __builtin_amdgcn_mfma_f32_16x16x32_bf16(afh[kt], bfl, acc[nt], 0, 0, 0);
        }
    }
    int rb = base + w * 16 + kg * 4;
    int bidx[4];
    if (POST == 1) {
        #pragma unroll
        for (int r = 0; r < 4; ++r)
            bidx[r] = (rb + r < NN) ? batch[rb + r] : 0;
    }
    #pragma unroll
    for (int nt = 0; nt < 4; ++nt) {
        int col = nt * 16 + ar;
        float bv = bias[col];
        float s = 0.f, q = 0.f;
        #pragma unroll
        for (int r = 0; r < 4; ++r) {
            int node = rb + r;
            float d = acc[nt][r] + bv;
            if (POST == 1) d = lrelu(d);
            if (node < NN) {
                out[(size_t)node * 64 + col] = d;
                if (POST == 1)
                    atomicAdd(&pool[(size_t)bidx[r] * 64 + col], d);
            }
            if (POST == 0) {
                d = (node < NN) ? d : 0.f;
                s += d; q += d * d;
            }
        }
        if (POST == 0) {
            s += __shfl_xor(s, 16); s += __shfl_xor(s, 32);
            q += __shfl_xor(q, 16); q += __shfl_xor(q, 32);
            if (kg == 0) { red[w * 128 + col] = s; red[w * 128 + 64 + col] = q; }
        }
    }
    if (POST == 0) {
        __syncthreads();
        if (t < 128) {
            int c = t & 63, which = t >> 6;
            float v = red[0 * 128 + which * 64 + c] + red[1 * 128 + which * 64 + c]
                    + red[2 * 128 + which * 64 + c] + red[3 * 128 + which * 64 + c];
            atomicAdd(&statsOut[which * 64 + c], v);
        }
    }
}

// ---- split-bf16 MFMA [N,128]@Wt+b, 64-col blocks.
template<int MODE>
__global__ __launch_bounds__(256) void k_cmm_f(
    const float* __restrict__ inA, const float* __restrict__ pool,
    const int* __restrict__ batch, const float* __restrict__ statsIn,
    const float* __restrict__ gIn, const float* __restrict__ bIn,
    const unsigned short* __restrict__ Wh, const unsigned short* __restrict__ Wl,
    const float* __restrict__ bias,
    float* __restrict__ out, float* __restrict__ statsOut)
{
    __shared__ unsigned short Ash[64 * 128], Asl[64 * 128];
    __shared__ unsigned short Bsh[64 * 128], Bsl[64 * 128];
    __shared__ float sc[128], sh[128];
    __shared__ float red[4 * 128];
    int t = threadIdx.x;
    int base = (blockIdx.x >> 1) * 64;
    int ncol0 = (blockIdx.x & 1) * 64;
    if (MODE == 1 && t < 128) {
        float m = statsIn[t] * (1.f / NN);
        float v = statsIn[128 + t] * (1.f / NN) - m * m;
        float s = gIn[t] * rsqrtf(v + BN_EPS);
        sc[t] = s; sh[t] = bIn[t] - m * s;
    }
    for (int i = t; i < 1024; i += 256) {
        int n = i >> 4, cb = i & 15;
        int idx = n * 16 + (cb ^ (n & 7));
        ((uint4*)Bsh)[idx] = ((const uint4*)Wh)[(ncol0 + n) * 16 + cb];
        ((uint4*)Bsl)[idx] = ((const uint4*)Wl)[(ncol0 + n) * 16 + cb];
    }
    __syncthreads();
    for (int i = t; i < 1024; i += 256) {
        int row = i >> 4, cb = i & 15;
        int node = base + row;
        float v[8] = {0.f, 0.f, 0.f, 0.f, 0.f, 0.f, 0.f, 0.f};
        if (node < NN) {
            const float* sp;
            if (MODE == 0) {
                sp = (cb < 8) ? (inA + (size_t)node * 64 + cb * 8)
                              : (pool + (size_t)batch[node] * 64 + (cb - 8) * 8);
            } else {
                sp = inA + (size_t)node * 128 + cb * 8;
            }
            float4 u0 = *(const float4*)sp;
            float4 u1 = *(const float4*)(sp + 4);
            v[0] = u0.x; v[1] = u0.y; v[2] = u0.z; v[3] = u0.w;
            v[4] = u1.x; v[5] = u1.y; v[6] = u1.z; v[7] = u1.w;
            if (MODE == 1) {
                #pragma unroll
                for (int j = 0; j < 8; ++j) {
                    int c = cb * 8 + j;
                    v[j] = lrelu(fmaf(v[j], sc[c], sh[c]));
                }
            }
        }
        unsigned hw[4], lw[4];
        #pragma unroll
        for (int j = 0; j < 4; ++j) {
            unsigned short h0 = f2bf(v[2 * j]), h1 = f2bf(v[2 * j + 1]);
            unsigned short l0 = f2bf(v[2 * j] - bf2f(h0)), l1 = f2bf(v[2 * j + 1] - bf2f(h1));
            hw[j] = (unsigned)h0 | ((unsigned)h1 << 16);
            lw[j] = (unsigned)l0 | ((unsigned)l1 << 16);
        }
        uint4 rh = { hw[0], hw[1], hw[2], hw[3] };
        uint4 rl = { lw[0], lw[1], lw[2], lw[3] };
        int idx = row * 16 + (cb ^ (row & 7));
        ((uint4*)Ash)[idx] = rh;
        ((uint4*)Asl)[idx] = rl;
    }
    __syncthreads();

    int w = t >> 6, l = t & 63;
    int ar = l & 15, kg = l >> 4;
    bf16x8 afh[4], afl[4];
    #pragma unroll
    for (int kt = 0; kt < 4; ++kt) {
        int row = w * 16 + ar, cb = kt * 4 + kg;
        int idx = row * 16 + (cb ^ (row & 7));
        afh[kt] = ((const bf16x8*)Ash)[idx];
        afl[kt] = ((const bf16x8*)Asl)[idx];
    }
    f32x4 acc[4];
    #pragma unroll
    for (int nt = 0; nt < 4; ++nt) { acc[nt][0] = 0.f; acc[nt][1] = 0.f; acc[nt][2] = 0.f; acc[nt][3] = 0.f; }
    #pragma unroll
    for (int nt = 0; nt < 4; ++nt) {
        #pragma unroll
        for (int kt = 0; kt < 4; ++kt) {
            int n = nt * 16 + ar, cb = kt * 4 + kg;
            int idx = n * 16 + (cb ^ (n & 7));
            bf16x8 bfh = ((const bf16x8*)Bsh)[idx];
            bf16x8 bfl = ((const bf16x8*)Bsl)[idx];
            acc[nt] = __builtin_amdgcn_mfma_f32_16x16x32_bf16(afh[kt], bfh, acc[nt], 0, 0, 0);
            acc[nt] = __builtin_amdgcn_mfma_f32_16x16x32_bf16(afl[kt], bfh, acc[nt], 0, 0, 0);
            acc[nt] = __builtin_amdgcn_mfma_f32_16x16x32_bf16(afh[kt], bfl, acc[nt], 0, 0, 0);
        }
    }
    int rb = base + w * 16 + kg * 4;
    #pragma unroll
    for (int nt = 0; nt < 4; ++nt) {
        int colg = ncol0 + nt * 16 + ar;
        float bv = bias[colg];
        float s = 0.f, q = 0.f;
        #pragma unroll
        for (int r = 0; r < 4; ++r) {
            int node = rb + r;
            float d = acc[nt][r] + bv;
            if (node < NN) out[(size_t)node * 128 + colg] = d;
            d = (node < NN) ? d : 0.f;
            s += d; q += d * d;
        }
        s += __shfl_xor(s, 16); s += __shfl_xor(s, 32);
        q += __shfl_xor(q, 16); q += __shfl_xor(q, 32);
        int col = nt * 16 + ar;
        if (kg == 0) { red[w * 128 + col] = s; red[w * 128 + 64 + col] = q; }
    }
    __syncthreads();
    if (t < 128) {
        int c = t & 63, which = t >> 6;
        float v = red[0 * 128 + which * 64 + c] + red[1 * 128 + which * 64 + c]
                + red[2 * 128 + which * 64 + c] + red[3 * 128 + which * 64 + c];
        atomicAdd(&statsOut[which * 128 + ncol0 + c], v);
    }
}

// ---- fused: x = lrelu(bn(h)); aggrOut = (1+eps[nextLayer]) * x
__global__ __launch_bounds__(256) void k_bn2(
    const float* __restrict__ in, const float* __restrict__ stats,
    const float* __restrict__ g, const float* __restrict__ b,
    const float* __restrict__ eps, int nextLayer,
    float* __restrict__ xout, float* __restrict__ aggrOut)
{
    int tid = blockIdx.x * 256 + threadIdx.x;
    float e1 = 1.f + eps[nextLayer];
    for (int i = tid; i < NN * 16; i += gridDim.x * 256) {
        int c4 = (i & 15) << 2;
        float4 v = ((const float4*)in)[i];
        float o[4] = {v.x, v.y, v.z, v.w};
        #pragma unroll
        for (int j = 0; j < 4; ++j) {
            int c = c4 + j;
            float m = stats[c] * (1.f / NN);
            float vv = stats[64 + c] * (1.f / NN) - m * m;
            float s = g[c] * rsqrtf(vv + BN_EPS);
            o[j] = lrelu(fmaf(o[j] - m, s, b[c]));
        }
        float4 r = {o[0], o[1], o[2], o[3]};
        ((float4*)xout)[i] = r;
        float4 r2 = {o[0] * e1, o[1] * e1, o[2] * e1, o[3] * e1};
        ((float4*)aggrOut)[i] = r2;
    }
}

// ---- out[n] = lrelu(bn(h128[n])) . cW3 + cb3
__global__ __launch_bounds__(256) void k_out(
    const float* __restrict__ h, const float* __restrict__ stats,
    const float* __restrict__ g, const float* __restrict__ b,
    const float* __restrict__ W3, const float* __restrict__ b3,
    float* __restrict__ outv)
{
    int lane = threadIdx.x & 63;
    int wid = (blockIdx.x * 256 + threadIdx.x) >> 6;
    int nw = (gridDim.x * 256) >> 6;
    float m0 = stats[lane] * (1.f / NN);
    float v0 = stats[128 + lane] * (1.f / NN) - m0 * m0;
    float s0 = g[lane] * rsqrtf(v0 + BN_EPS);
    float h0 = b[lane] - m0 * s0;
    float m1 = stats[64 + lane] * (1.f / NN);
    float v1 = stats[128 + 64 + lane] * (1.f / NN) - m1 * m1;
    float s1 = g[64 + lane] * rsqrtf(v1 + BN_EPS);
    float h1 = b[64 + lane] - m1 * s1;
    float w0 = W3[lane], w1 = W3[64 + lane];
    float bb = b3[0];
    for (int n = wid; n < NN; n += nw) {
        float a = h[(size_t)n * 128 + lane];
        float c = h[(size_t)n * 128 + 64 + lane];
        a = lrelu(fmaf(a, s0, h0));
        c = lrelu(fmaf(c, s1, h1));
        float p = a * w0 + c * w1;
        p += __shfl_xor(p, 32);
        p += __shfl_xor(p, 16);
        p += __shfl_xor(p, 8);
        p += __shfl_xor(p, 4);
        p += __shfl_xor(p, 2);
        p += __shfl_xor(p, 1);
        if (lane == 0) outv[n] = p + bb;
    }
}

extern "C" void kernel_launch(void* const* d_in, const int* in_sizes, int n_in,
                              void* d_out, int out_size, void* d_ws, size_t ws_size,
                              hipStream_t stream)
{
    const float* x0   = (const float*)d_in[0];
    const float* ea   = (const float*)d_in[1];
    const float* leW  = (const float*)d_in[2];
    const float* leb  = (const float*)d_in[3];
    const float* W1   = (const float*)d_in[4];
    const float* b1   = (const float*)d_in[5];
    const float* g1   = (const float*)d_in[6];
    const float* bb1  = (const float*)d_in[7];
    const float* W2   = (const float*)d_in[8];
    const float* b2   = (const float*)d_in[9];
    const float* eps  = (const float*)d_in[10];
    const float* og   = (const float*)d_in[11];
    const float* ob   = (const float*)d_in[12];
    const float* cW1  = (const float*)d_in[13];
    const float* cb1  = (const float*)d_in[14];
    const float* cg1  = (const float*)d_in[15];
    const float* cbb1 = (const float*)d_in[16];
    const float* cW2  = (const float*)d_in[17];
    const float* cb2  = (const float*)d_in[18];
    const float* cg2  = (const float*)d_in[19];
    const float* cbb2 = (const float*)d_in[20];
    const float* cW3  = (const float*)d_in[21];
    const float* cb3  = (const float*)d_in[22];
    const int* ei     = (const int*)d_in[23];
    const int* batch  = (const int*)d_in[24];
    const int* src = ei;
    const int* dst = ei + NE;

    // ---- workspace layout (4-byte units). eaz aliases h128 (disjoint lifetimes).
    float* xbuf   = (float*)d_ws;                       // NN*64
    float* hbuf   = xbuf + (size_t)NN * 64;             // NN*64
    unsigned short* eaz = (unsigned short*)(hbuf + (size_t)NN * 64); // NE*32 ushort (64B/edge)
    float* h128   = (float*)eaz;                        // NN*128 (head) — alias
    float* pool   = (float*)(eaz + (size_t)NE * 32);    // NG*64
    float* cstats = pool + (size_t)NG * 64;             // 512
    float* stats  = cstats + 512;                       // 768 (3 x 256)
    int*   cnt    = (int*)(stats + 768);                // NN
    int*   off    = cnt + NN;                           // NN+1 (+pad)
    int*   cur    = off + NN + 4;                       // NN
    int*   bsum   = cur + NN;                           // 256
    int*   boff   = bsum + 256;                         // 256
    unsigned short* w1h  = (unsigned short*)(boff + 256); // 3*4096 each
    unsigned short* w1l  = w1h + 3 * 4096;
    unsigned short* w2h  = w1l + 3 * 4096;
    unsigned short* w2l  = w2h + 3 * 4096;
    unsigned short* cw1h = w2l + 3 * 4096;              // 16384 each
    unsigned short* cw1l = cw1h + 16384;
    unsigned short* cw2h = cw1l + 16384;
    unsigned short* cw2l = cw2h + 16384;
    float* outp   = (float*)d_out;

    int zeroN = NG * 64 + 512 + 768 + NN;  // pool..cnt contiguous

    int fGrid  = (NN + 63) / 64;            // 782 (MFMA GEMMs)
    int aGrid  = (NCHUNK + 31) / 32;        // 1563 (k_aggr_m: 32 chunks/block)

    // ---- one-time: zero, weight cvt, CSR build, fused scatter+convert
    k_prep<<<512, 256, 0, stream>>>((int*)pool, zeroN);
    k_wcvt<<<8, 256, 0, stream>>>(W1, W2, cW1, cW2, w1h, w1l, w2h, w2l,
                                  cw1h, cw1l, cw2h, cw2l);
    k_hist<<<1024, 256, 0, stream>>>(dst, cnt);
    k_scanA<<<NB_SCAN, 256, 0, stream>>>(cnt, off, bsum);
    k_scanB<<<1, 256, 0, stream>>>(bsum, boff);
    k_scanC<<<NB_SCAN, 256, 0, stream>>>(cnt, off, boff, cur);
    k_scatter2<<<2048, 256, 0, stream>>>(src, dst, cur, ea, eaz);

    k_init<<<1024, 256, 0, stream>>>(x0, eps, 0, hbuf);
    for (int l = 0; l < 3; ++l) {
        const float* xc = (l == 0) ? x0 : xbuf;
        float* st = stats + l * 256;
        k_aggr_m<<<aGrid, 256, 0, stream>>>(xc, eaz,
                leW + l * 1024, leb + l * 64, hbuf);
        k_mm64_f<0, 0><<<fGrid, 256, 0, stream>>>(hbuf, w1h + l * 4096, w1l + l * 4096,
                b1 + l * 64, nullptr, nullptr, nullptr, hbuf, st, nullptr, nullptr);
        if (l < 2) {
            k_mm64_f<1, 0><<<fGrid, 256, 0, stream>>>(hbuf, w2h + l * 4096, w2l + l * 4096,
                    b2 + l * 64, st, g1 + l * 64, bb1 + l * 64, hbuf, st + 128,
                    nullptr, nullptr);
            k_bn2<<<1024, 256, 0, stream>>>(hbuf, st + 128, og + l * 64, ob + l * 64,
                    eps, l + 1, xbuf, hbuf);
        } else {
            k_mm64_f<1, 1><<<fGrid, 256, 0, stream>>>(hbuf, w2h + l * 4096, w2l + l * 4096,
                    b2 + l * 64, st, g1 + l * 64, bb1 + l * 64, xbuf, nullptr,
                    batch, pool);
        }
    }
    k_cmm_f<0><<<fGrid * 2, 256, 0, stream>>>(xbuf, pool, batch, nullptr, nullptr, nullptr,
                                              cw1h, cw1l, cb1, h128, cstats);
    k_cmm_f<1><<<fGrid * 2, 256, 0, stream>>>(h128, nullptr, nullptr, cstats, cg1, cbb1,
                                              cw2h, cw2l, cb2, h128, cstats + 256);
    k_out<<<1024, 256, 0, stream>>>(h128, cstats + 256, cg2, cbb2, cW3, cb3, outp);
}